// Round 1
// baseline (1178.195 us; speedup 1.0000x reference)
//
#include <hip/hip_runtime.h>

#define NB    4
#define NSEQ  1024
#define DMODEL 768
#define NH    12
#define DH    64

static __device__ __forceinline__ float bf2f(unsigned short u) {
    return __uint_as_float(((unsigned)u) << 16);
}
static __device__ __forceinline__ unsigned short f2bf(float f) {
    unsigned u = __float_as_uint(f);
    u += 0x7FFFu + ((u >> 16) & 1u);   // round-to-nearest-even
    return (unsigned short)(u >> 16);
}

// ---------------------------------------------------------------------------
// Kernel 1: QKV projection. x[4096,768] @ W[768,768] -> bf16 outputs.
//   z=0: Q[b][n][h][d]  (*1/8)      = [4096,768] natural
//   z=1: Kt[b][h][d][n]             (transposed for coalesced score loads)
//   z=2: V[b][h][n][d]
// ---------------------------------------------------------------------------
__global__ __launch_bounds__(256) void qkv_gemm(
    const float* __restrict__ x, const float* __restrict__ Wq,
    const float* __restrict__ Wk, const float* __restrict__ Wv,
    unsigned short* __restrict__ Q, unsigned short* __restrict__ Kt,
    unsigned short* __restrict__ V)
{
    const int z = blockIdx.z;
    const float* __restrict__ W = (z == 0) ? Wq : (z == 1) ? Wk : Wv;
    const int r0 = blockIdx.x * 64;
    const int c0 = blockIdx.y * 64;
    const int t  = threadIdx.x;
    const int tx = t & 15, ty = t >> 4;

    __shared__ float xs[16][65];   // [kk][r_local]
    __shared__ float ws[16][65];   // [kk][c_local]

    float acc[4][4] = {};
    const int xr = t >> 2, xk = (t & 3) * 4;
    const int wk = t >> 4, wc = (t & 15) * 4;

    for (int k0 = 0; k0 < DMODEL; k0 += 16) {
        float4 xa = *(const float4*)(x + (size_t)(r0 + xr) * DMODEL + k0 + xk);
        float4 wa = *(const float4*)(W + (size_t)(k0 + wk) * DMODEL + c0 + wc);
        __syncthreads();
        xs[xk + 0][xr] = xa.x; xs[xk + 1][xr] = xa.y;
        xs[xk + 2][xr] = xa.z; xs[xk + 3][xr] = xa.w;
        *(float4*)&ws[wk][wc] = wa;
        __syncthreads();
        #pragma unroll
        for (int kk = 0; kk < 16; kk++) {
            float a0 = xs[kk][ty * 4 + 0], a1 = xs[kk][ty * 4 + 1];
            float a2 = xs[kk][ty * 4 + 2], a3 = xs[kk][ty * 4 + 3];
            float b0 = ws[kk][tx * 4 + 0], b1 = ws[kk][tx * 4 + 1];
            float b2 = ws[kk][tx * 4 + 2], b3 = ws[kk][tx * 4 + 3];
            acc[0][0] = fmaf(a0, b0, acc[0][0]); acc[0][1] = fmaf(a0, b1, acc[0][1]);
            acc[0][2] = fmaf(a0, b2, acc[0][2]); acc[0][3] = fmaf(a0, b3, acc[0][3]);
            acc[1][0] = fmaf(a1, b0, acc[1][0]); acc[1][1] = fmaf(a1, b1, acc[1][1]);
            acc[1][2] = fmaf(a1, b2, acc[1][2]); acc[1][3] = fmaf(a1, b3, acc[1][3]);
            acc[2][0] = fmaf(a2, b0, acc[2][0]); acc[2][1] = fmaf(a2, b1, acc[2][1]);
            acc[2][2] = fmaf(a2, b2, acc[2][2]); acc[2][3] = fmaf(a2, b3, acc[2][3]);
            acc[3][0] = fmaf(a3, b0, acc[3][0]); acc[3][1] = fmaf(a3, b1, acc[3][1]);
            acc[3][2] = fmaf(a3, b2, acc[3][2]); acc[3][3] = fmaf(a3, b3, acc[3][3]);
        }
    }

    if (z == 0) {
        #pragma unroll
        for (int i = 0; i < 4; i++) {
            int r = r0 + ty * 4 + i;
            ushort4 o;
            o.x = f2bf(acc[i][0] * 0.125f); o.y = f2bf(acc[i][1] * 0.125f);
            o.z = f2bf(acc[i][2] * 0.125f); o.w = f2bf(acc[i][3] * 0.125f);
            *(ushort4*)(Q + (size_t)r * DMODEL + c0 + tx * 4) = o;
        }
    } else if (z == 1) {
        const int h = c0 >> 6;
        const int r = r0 + ty * 4;
        const int b = r >> 10, n = r & 1023;
        #pragma unroll
        for (int j = 0; j < 4; j++) {
            const int d = tx * 4 + j;
            ushort4 o;
            o.x = f2bf(acc[0][j]); o.y = f2bf(acc[1][j]);
            o.z = f2bf(acc[2][j]); o.w = f2bf(acc[3][j]);
            *(ushort4*)(Kt + (((size_t)b * NH + h) * DH + d) * NSEQ + n) = o;
        }
    } else {
        const int h = c0 >> 6;
        #pragma unroll
        for (int i = 0; i < 4; i++) {
            int r = r0 + ty * 4 + i;
            int b = r >> 10, n = r & 1023;
            ushort4 o;
            o.x = f2bf(acc[i][0]); o.y = f2bf(acc[i][1]);
            o.z = f2bf(acc[i][2]); o.w = f2bf(acc[i][3]);
            *(ushort4*)(V + (((size_t)b * NH + h) * NSEQ + n) * DH + tx * 4) = o;
        }
    }
}

// ---------------------------------------------------------------------------
// block-wide reduction of 12 per-thread values (max or sum), result in out12
// ---------------------------------------------------------------------------
static __device__ __forceinline__ void reduce12(
    const float* v, float* out12, float* red, int t, bool is_max)
{
    const int lane = t & 63, w = t >> 6;
    #pragma unroll
    for (int h = 0; h < 12; h++) {
        float x = v[h];
        #pragma unroll
        for (int off = 32; off > 0; off >>= 1) {
            float o = __shfl_down(x, off, 64);
            x = is_max ? fmaxf(x, o) : (x + o);
        }
        if (lane == 0) red[w * 12 + h] = x;
    }
    __syncthreads();
    if (t < 12) {
        float x = red[t];
        #pragma unroll
        for (int w2 = 1; w2 < 4; w2++) {
            float o = red[w2 * 12 + t];
            x = is_max ? fmaxf(x, o) : (x + o);
        }
        out12[t] = x;
    }
    __syncthreads();
}

// ---------------------------------------------------------------------------
// Kernel 2: per (b, q): scores for all 12 heads over all k (in registers,
// 4 k per thread), softmax, theta mix (normalization folded into theta),
// LayerNorm over k, write bf16 A[bi][i][q][k].
// ---------------------------------------------------------------------------
__global__ __launch_bounds__(256) void attn_mix_ln(
    const unsigned short* __restrict__ Q, const unsigned short* __restrict__ Kt,
    const float* __restrict__ theta, const float* __restrict__ ln_scale,
    const float* __restrict__ ln_bias, unsigned short* __restrict__ A,
    int b_start)
{
    const int q  = blockIdx.x;
    const int bi = blockIdx.y;
    const int b  = b_start + bi;
    const int t  = threadIdx.x;

    __shared__ float qv[DMODEL];
    __shared__ float th_s[144];
    __shared__ float red[48];
    __shared__ float l_m[12], l_l[12], l_sum[12], l_sum2[12], l_mean[12], l_rstd[12];

    const unsigned short* qp = Q + ((size_t)b * NSEQ + q) * DMODEL;
    for (int idx = t; idx < DMODEL; idx += 256) qv[idx] = bf2f(qp[idx]);
    __syncthreads();

    const int k0 = t * 4;                 // this thread owns k0..k0+3
    float sc[12][4];

    // ---- scores: S[h][k] = q_h . k_k  (Q pre-scaled by 1/8) ----
    #pragma unroll
    for (int h = 0; h < NH; h++) {
        float s0 = 0.f, s1 = 0.f, s2 = 0.f, s3 = 0.f;
        const unsigned short* kp = Kt + (((size_t)b * NH + h) * DH) * NSEQ + k0;
        #pragma unroll 8
        for (int d = 0; d < DH; d++) {
            float qd = qv[h * DH + d];
            ushort4 kk = *(const ushort4*)(kp + (size_t)d * NSEQ);
            s0 = fmaf(qd, bf2f(kk.x), s0);
            s1 = fmaf(qd, bf2f(kk.y), s1);
            s2 = fmaf(qd, bf2f(kk.z), s2);
            s3 = fmaf(qd, bf2f(kk.w), s3);
        }
        sc[h][0] = s0; sc[h][1] = s1; sc[h][2] = s2; sc[h][3] = s3;
    }

    // ---- softmax stats ----
    float r12[12];
    #pragma unroll
    for (int h = 0; h < 12; h++)
        r12[h] = fmaxf(fmaxf(sc[h][0], sc[h][1]), fmaxf(sc[h][2], sc[h][3]));
    reduce12(r12, l_m, red, t, true);

    #pragma unroll
    for (int h = 0; h < 12; h++) {
        float m = l_m[h];
        sc[h][0] = __expf(sc[h][0] - m);
        sc[h][1] = __expf(sc[h][1] - m);
        sc[h][2] = __expf(sc[h][2] - m);
        sc[h][3] = __expf(sc[h][3] - m);
        r12[h] = sc[h][0] + sc[h][1] + sc[h][2] + sc[h][3];
    }
    reduce12(r12, l_l, red, t, false);

    // theta with softmax normalization folded in: th_s[h][i] = theta[h][i]/l_h
    if (t < 144) th_s[t] = theta[t] * (1.0f / l_l[t / 12]);
    __syncthreads();

    // ---- theta mix (in place), accumulate LN stats ----
    float sT[12] = {}, sT2[12] = {};
    #pragma unroll
    for (int j = 0; j < 4; j++) {
        float col[12];
        #pragma unroll
        for (int h = 0; h < 12; h++) col[h] = sc[h][j];
        #pragma unroll
        for (int i = 0; i < 12; i++) {
            float s = 0.f;
            #pragma unroll
            for (int h = 0; h < 12; h++) s = fmaf(th_s[h * 12 + i], col[h], s);
            sc[i][j] = s;
            sT[i] += s;
            sT2[i] = fmaf(s, s, sT2[i]);
        }
    }
    reduce12(sT,  l_sum,  red, t, false);
    reduce12(sT2, l_sum2, red, t, false);
    if (t < 12) {
        float mean = l_sum[t] * (1.0f / 1024.0f);
        float var  = l_sum2[t] * (1.0f / 1024.0f) - mean * mean;
        l_mean[t] = mean;
        l_rstd[t] = rsqrtf(var + 1e-6f);
    }
    __syncthreads();

    // ---- LayerNorm + write A (bf16) ----
    float4 s4 = *(const float4*)(ln_scale + k0);
    float4 b4 = *(const float4*)(ln_bias + k0);
    unsigned short* Ap = A + (((size_t)bi * NH * NSEQ + q) * NSEQ) + k0;
    #pragma unroll
    for (int i = 0; i < 12; i++) {
        float m = l_mean[i], rs = l_rstd[i];
        ushort4 o;
        o.x = f2bf(fmaf((sc[i][0] - m) * rs, s4.x, b4.x));
        o.y = f2bf(fmaf((sc[i][1] - m) * rs, s4.y, b4.y));
        o.z = f2bf(fmaf((sc[i][2] - m) * rs, s4.z, b4.z));
        o.w = f2bf(fmaf((sc[i][3] - m) * rs, s4.w, b4.w));
        *(ushort4*)(Ap + (size_t)i * NSEQ * NSEQ) = o;
    }
}

// ---------------------------------------------------------------------------
// Kernel 3: out[b][k][i*64+d] = sum_q A[bi][i][q][k] * V[b][i][q][d]
// 64(k) x 64(d) tile per block, K-loop over q in chunks of 32.
// ---------------------------------------------------------------------------
__global__ __launch_bounds__(256) void av_gemm(
    const unsigned short* __restrict__ A, const unsigned short* __restrict__ V,
    float* __restrict__ out, int b_start)
{
    const int bi = blockIdx.z;
    const int b  = b_start + bi;
    const int i  = blockIdx.y;
    const int kk0 = blockIdx.x * 64;
    const int t  = threadIdx.x;
    const int tx = t & 15, ty = t >> 4;

    __shared__ float As[32][65];   // [qq][k_local]
    __shared__ float Vs[32][65];   // [qq][d]

    float acc[4][4] = {};
    const unsigned short* Ai = A + ((size_t)bi * NH + i) * NSEQ * NSEQ;
    const unsigned short* Vi = V + ((size_t)b  * NH + i) * NSEQ * DH;

    const int lq = t >> 3, lc = (t & 7) * 8;

    for (int q0 = 0; q0 < NSEQ; q0 += 32) {
        const unsigned short* ap = Ai + (size_t)(q0 + lq) * NSEQ + kk0 + lc;
        ushort4 a0 = *(const ushort4*)ap;
        ushort4 a1 = *(const ushort4*)(ap + 4);
        const unsigned short* vp = Vi + (size_t)(q0 + lq) * DH + lc;
        ushort4 v0 = *(const ushort4*)vp;
        ushort4 v1 = *(const ushort4*)(vp + 4);
        __syncthreads();
        As[lq][lc + 0] = bf2f(a0.x); As[lq][lc + 1] = bf2f(a0.y);
        As[lq][lc + 2] = bf2f(a0.z); As[lq][lc + 3] = bf2f(a0.w);
        As[lq][lc + 4] = bf2f(a1.x); As[lq][lc + 5] = bf2f(a1.y);
        As[lq][lc + 6] = bf2f(a1.z); As[lq][lc + 7] = bf2f(a1.w);
        Vs[lq][lc + 0] = bf2f(v0.x); Vs[lq][lc + 1] = bf2f(v0.y);
        Vs[lq][lc + 2] = bf2f(v0.z); Vs[lq][lc + 3] = bf2f(v0.w);
        Vs[lq][lc + 4] = bf2f(v1.x); Vs[lq][lc + 5] = bf2f(v1.y);
        Vs[lq][lc + 6] = bf2f(v1.z); Vs[lq][lc + 7] = bf2f(v1.w);
        __syncthreads();
        #pragma unroll
        for (int qq = 0; qq < 32; qq++) {
            float a0f = As[qq][ty * 4 + 0], a1f = As[qq][ty * 4 + 1];
            float a2f = As[qq][ty * 4 + 2], a3f = As[qq][ty * 4 + 3];
            float b0f = Vs[qq][tx * 4 + 0], b1f = Vs[qq][tx * 4 + 1];
            float b2f = Vs[qq][tx * 4 + 2], b3f = Vs[qq][tx * 4 + 3];
            acc[0][0] = fmaf(a0f, b0f, acc[0][0]); acc[0][1] = fmaf(a0f, b1f, acc[0][1]);
            acc[0][2] = fmaf(a0f, b2f, acc[0][2]); acc[0][3] = fmaf(a0f, b3f, acc[0][3]);
            acc[1][0] = fmaf(a1f, b0f, acc[1][0]); acc[1][1] = fmaf(a1f, b1f, acc[1][1]);
            acc[1][2] = fmaf(a1f, b2f, acc[1][2]); acc[1][3] = fmaf(a1f, b3f, acc[1][3]);
            acc[2][0] = fmaf(a2f, b0f, acc[2][0]); acc[2][1] = fmaf(a2f, b1f, acc[2][1]);
            acc[2][2] = fmaf(a2f, b2f, acc[2][2]); acc[2][3] = fmaf(a2f, b3f, acc[2][3]);
            acc[3][0] = fmaf(a3f, b0f, acc[3][0]); acc[3][1] = fmaf(a3f, b1f, acc[3][1]);
            acc[3][2] = fmaf(a3f, b2f, acc[3][2]); acc[3][3] = fmaf(a3f, b3f, acc[3][3]);
        }
    }

    #pragma unroll
    for (int ii = 0; ii < 4; ii++) {
        int k = kk0 + ty * 4 + ii;
        float4 o = make_float4(acc[ii][0], acc[ii][1], acc[ii][2], acc[ii][3]);
        *(float4*)(out + ((size_t)b * NSEQ + k) * DMODEL + i * DH + tx * 4) = o;
    }
}

extern "C" void kernel_launch(void* const* d_in, const int* in_sizes, int n_in,
                              void* d_out, int out_size, void* d_ws, size_t ws_size,
                              hipStream_t stream) {
    const float* x     = (const float*)d_in[0];
    const float* Wq    = (const float*)d_in[1];
    const float* Wk    = (const float*)d_in[2];
    const float* Wv    = (const float*)d_in[3];
    const float* theta = (const float*)d_in[4];
    const float* ln_s  = (const float*)d_in[5];
    const float* ln_b  = (const float*)d_in[6];
    float* out = (float*)d_out;

    char* ws = (char*)d_ws;
    const size_t qsz = (size_t)NB * NSEQ * DMODEL * sizeof(unsigned short); // 6.29 MB
    unsigned short* Q  = (unsigned short*)(ws);
    unsigned short* Kt = (unsigned short*)(ws + qsz);
    unsigned short* V  = (unsigned short*)(ws + 2 * qsz);
    unsigned short* A  = (unsigned short*)(ws + 3 * qsz);
    const size_t a_full = (size_t)NB * NH * NSEQ * NSEQ * sizeof(unsigned short); // 100.7 MB
    const bool full = ws_size >= 3 * qsz + a_full;

    qkv_gemm<<<dim3(NB * NSEQ / 64, DMODEL / 64, 3), 256, 0, stream>>>(
        x, Wq, Wk, Wv, Q, Kt, V);

    if (full) {
        attn_mix_ln<<<dim3(NSEQ, NB), 256, 0, stream>>>(
            Q, Kt, theta, ln_s, ln_b, A, 0);
        av_gemm<<<dim3(NSEQ / 64, NH, NB), 256, 0, stream>>>(A, V, out, 0);
    } else {
        for (int b = 0; b < NB; b++) {
            attn_mix_ln<<<dim3(NSEQ, 1), 256, 0, stream>>>(
                Q, Kt, theta, ln_s, ln_b, A, b);
            av_gemm<<<dim3(NSEQ / 64, NH, 1), 256, 0, stream>>>(A, V, out, b);
        }
    }
}

// Round 2
// 695.232 us; speedup vs baseline: 1.6947x; 1.6947x over previous
//
#include <hip/hip_runtime.h>

#define NB    4
#define NSEQ  1024
#define DMODEL 768
#define NH    12
#define DH    64

typedef __bf16 bf16x8 __attribute__((ext_vector_type(8)));
typedef float  floatx4 __attribute__((ext_vector_type(4)));

static __device__ __forceinline__ float bf2f(unsigned short u) {
    return __uint_as_float(((unsigned)u) << 16);
}
static __device__ __forceinline__ unsigned short f2bf(float f) {
    unsigned u = __float_as_uint(f);
    u += 0x7FFFu + ((u >> 16) & 1u);   // round-to-nearest-even
    return (unsigned short)(u >> 16);
}

// ---------------------------------------------------------------------------
// Kernel 1: QKV projection. x[4096,768] @ W[768,768] -> bf16 outputs.
//   z=0: Q[b][n][h][d]  (*1/8)      = [4096,768] natural
//   z=1: K[b][h][n][d]
//   z=2: V[b][h][n][d]
// ---------------------------------------------------------------------------
__global__ __launch_bounds__(256) void qkv_gemm(
    const float* __restrict__ x, const float* __restrict__ Wq,
    const float* __restrict__ Wk, const float* __restrict__ Wv,
    unsigned short* __restrict__ Q, unsigned short* __restrict__ K,
    unsigned short* __restrict__ V)
{
    const int z = blockIdx.z;
    const float* __restrict__ W = (z == 0) ? Wq : (z == 1) ? Wk : Wv;
    const int r0 = blockIdx.x * 64;
    const int c0 = blockIdx.y * 64;
    const int t  = threadIdx.x;
    const int tx = t & 15, ty = t >> 4;

    __shared__ float xs[16][65];   // [kk][r_local]
    __shared__ float ws[16][65];   // [kk][c_local]

    float acc[4][4] = {};
    const int xr = t >> 2, xk = (t & 3) * 4;
    const int wk = t >> 4, wc = (t & 15) * 4;

    for (int k0 = 0; k0 < DMODEL; k0 += 16) {
        float4 xa = *(const float4*)(x + (size_t)(r0 + xr) * DMODEL + k0 + xk);
        float4 wa = *(const float4*)(W + (size_t)(k0 + wk) * DMODEL + c0 + wc);
        __syncthreads();
        xs[xk + 0][xr] = xa.x; xs[xk + 1][xr] = xa.y;
        xs[xk + 2][xr] = xa.z; xs[xk + 3][xr] = xa.w;
        *(float4*)&ws[wk][wc] = wa;
        __syncthreads();
        #pragma unroll
        for (int kk = 0; kk < 16; kk++) {
            float a0 = xs[kk][ty * 4 + 0], a1 = xs[kk][ty * 4 + 1];
            float a2 = xs[kk][ty * 4 + 2], a3 = xs[kk][ty * 4 + 3];
            float b0 = ws[kk][tx * 4 + 0], b1 = ws[kk][tx * 4 + 1];
            float b2 = ws[kk][tx * 4 + 2], b3 = ws[kk][tx * 4 + 3];
            acc[0][0] = fmaf(a0, b0, acc[0][0]); acc[0][1] = fmaf(a0, b1, acc[0][1]);
            acc[0][2] = fmaf(a0, b2, acc[0][2]); acc[0][3] = fmaf(a0, b3, acc[0][3]);
            acc[1][0] = fmaf(a1, b0, acc[1][0]); acc[1][1] = fmaf(a1, b1, acc[1][1]);
            acc[1][2] = fmaf(a1, b2, acc[1][2]); acc[1][3] = fmaf(a1, b3, acc[1][3]);
            acc[2][0] = fmaf(a2, b0, acc[2][0]); acc[2][1] = fmaf(a2, b1, acc[2][1]);
            acc[2][2] = fmaf(a2, b2, acc[2][2]); acc[2][3] = fmaf(a2, b3, acc[2][3]);
            acc[3][0] = fmaf(a3, b0, acc[3][0]); acc[3][1] = fmaf(a3, b1, acc[3][1]);
            acc[3][2] = fmaf(a3, b2, acc[3][2]); acc[3][3] = fmaf(a3, b3, acc[3][3]);
        }
    }

    if (z == 0) {
        #pragma unroll
        for (int i = 0; i < 4; i++) {
            int r = r0 + ty * 4 + i;
            ushort4 o;
            o.x = f2bf(acc[i][0] * 0.125f); o.y = f2bf(acc[i][1] * 0.125f);
            o.z = f2bf(acc[i][2] * 0.125f); o.w = f2bf(acc[i][3] * 0.125f);
            *(ushort4*)(Q + (size_t)r * DMODEL + c0 + tx * 4) = o;
        }
    } else {
        unsigned short* P = (z == 1) ? K : V;
        const int h = c0 >> 6;
        #pragma unroll
        for (int i = 0; i < 4; i++) {
            int r = r0 + ty * 4 + i;
            int b = r >> 10, n = r & 1023;
            ushort4 o;
            o.x = f2bf(acc[i][0]); o.y = f2bf(acc[i][1]);
            o.z = f2bf(acc[i][2]); o.w = f2bf(acc[i][3]);
            *(ushort4*)(P + (((size_t)b * NH + h) * NSEQ + n) * DH + tx * 4) = o;
        }
    }
}

// ---------------------------------------------------------------------------
// Kernel 2a: per (b,h): S = (Q_h/8) . K_h^T via MFMA 16x16x32 bf16,
// 128x128 tile per block (4 waves, 2x2 quadrants of 64x64).
// Writes P = exp(S) unnormalized, bf16, P[b][h][q][k].
// ---------------------------------------------------------------------------
__global__ __launch_bounds__(256) void score_gemm(
    const unsigned short* __restrict__ Q, const unsigned short* __restrict__ K,
    unsigned short* __restrict__ P)
{
    const int bh = blockIdx.z;        // b*12+h
    const int b  = bh / NH, h = bh % NH;
    const int q0 = blockIdx.x * 128;
    const int k0 = blockIdx.y * 128;
    const int t    = threadIdx.x;
    const int wave = t >> 6, lane = t & 63;

    __shared__ __align__(16) char sm[36864];
    unsigned short (*Qs)[72] = (unsigned short(*)[72])sm;            // 128 x 72
    unsigned short (*Ks)[72] = (unsigned short(*)[72])(sm + 18432);  // 128 x 72
    unsigned short (*Po)[136] = (unsigned short(*)[136])sm;          // epilogue reuse

    // stage Q tile [128 q][64 d] and K tile [128 k][64 d], 16B chunks
    #pragma unroll
    for (int i = 0; i < 4; i++) {
        int c = t + i * 256;              // 0..1023
        int row = c >> 3, off = (c & 7) * 8;
        uint4 qa = *(const uint4*)(Q + ((size_t)(b * NSEQ + q0 + row)) * DMODEL + h * DH + off);
        uint4 ka = *(const uint4*)(K + (((size_t)bh) * NSEQ + (k0 + row)) * DH + off);
        *(uint4*)&Qs[row][off] = qa;
        *(uint4*)&Ks[row][off] = ka;
    }
    __syncthreads();

    const int wq = (wave >> 1) * 64, wk2 = (wave & 1) * 64;
    const int m = lane & 15, g = lane >> 4;

    floatx4 acc[4][4] = {};
    #pragma unroll
    for (int ds = 0; ds < 2; ds++) {
        const int dd = ds * 32 + g * 8;
        bf16x8 af[4], bf[4];
        #pragma unroll
        for (int mt = 0; mt < 4; mt++)
            af[mt] = *(const bf16x8*)&Qs[wq + mt * 16 + m][dd];
        #pragma unroll
        for (int nt = 0; nt < 4; nt++)
            bf[nt] = *(const bf16x8*)&Ks[wk2 + nt * 16 + m][dd];
        #pragma unroll
        for (int mt = 0; mt < 4; mt++)
            #pragma unroll
            for (int nt = 0; nt < 4; nt++)
                acc[mt][nt] = __builtin_amdgcn_mfma_f32_16x16x32_bf16(
                    af[mt], bf[nt], acc[mt][nt], 0, 0, 0);
    }

    __syncthreads();   // done with Qs/Ks; reuse as Po
    #pragma unroll
    for (int mt = 0; mt < 4; mt++) {
        #pragma unroll
        for (int nt = 0; nt < 4; nt++) {
            int qloc = wq + mt * 16 + g * 4;
            int kloc = wk2 + nt * 16 + m;
            #pragma unroll
            for (int r = 0; r < 4; r++)
                Po[qloc + r][kloc] = f2bf(__expf(acc[mt][nt][r]));
        }
    }
    __syncthreads();

    // coalesced store of the 128x128 bf16 tile
    #pragma unroll
    for (int i = 0; i < 8; i++) {
        int c = t + i * 256;              // 0..2047
        int row = c >> 4, off = (c & 15) * 8;
        *(uint4*)(P + (((size_t)bh * NSEQ) + q0 + row) * NSEQ + k0 + off) =
            *(uint4*)&Po[row][off];
    }
}

// ---------------------------------------------------------------------------
// block-wide reduction of 12 per-thread values (max or sum), result in out12
// ---------------------------------------------------------------------------
static __device__ __forceinline__ void reduce12(
    const float* v, float* out12, float* red, int t, bool is_max)
{
    const int lane = t & 63, w = t >> 6;
    #pragma unroll
    for (int h = 0; h < 12; h++) {
        float x = v[h];
        #pragma unroll
        for (int off = 32; off > 0; off >>= 1) {
            float o = __shfl_down(x, off, 64);
            x = is_max ? fmaxf(x, o) : (x + o);
        }
        if (lane == 0) red[w * 12 + h] = x;
    }
    __syncthreads();
    if (t < 12) {
        float x = red[t];
        #pragma unroll
        for (int w2 = 1; w2 < 4; w2++) {
            float o = red[w2 * 12 + t];
            x = is_max ? fmaxf(x, o) : (x + o);
        }
        out12[t] = x;
    }
    __syncthreads();
}

// ---------------------------------------------------------------------------
// Kernel 2b: per (b,q): read P rows (12 heads, unnormalized exp), row-sum ->
// softmax denominators, theta mix (1/l folded into theta), LayerNorm over k,
// write A bf16 IN PLACE over P (same layout, block-exclusive slice).
// ---------------------------------------------------------------------------
__global__ __launch_bounds__(256) void mix_ln(
    unsigned short* __restrict__ P, const float* __restrict__ theta,
    const float* __restrict__ ln_scale, const float* __restrict__ ln_bias)
{
    const int q = blockIdx.x;
    const int b = blockIdx.y;
    const int t = threadIdx.x;

    __shared__ float th_s[144];
    __shared__ float red[48];
    __shared__ float l_l[12], l_sum[12], l_sum2[12], l_mean[12], l_rstd[12];

    const int k0 = t * 4;                 // this thread owns k0..k0+3
    float p[12][4];
    float r12[12];

    #pragma unroll
    for (int h = 0; h < NH; h++) {
        ushort4 u = *(const ushort4*)(P + (((size_t)(b * NH + h)) * NSEQ + q) * NSEQ + k0);
        p[h][0] = bf2f(u.x); p[h][1] = bf2f(u.y);
        p[h][2] = bf2f(u.z); p[h][3] = bf2f(u.w);
        r12[h] = (p[h][0] + p[h][1]) + (p[h][2] + p[h][3]);
    }
    reduce12(r12, l_l, red, t, false);

    // theta with softmax normalization folded in: th_s[h][i] = theta[h][i]/l_h
    if (t < 144) th_s[t] = theta[t] * (1.0f / l_l[t / 12]);
    __syncthreads();

    // ---- theta mix, accumulate LN stats ----
    float sc[12][4];
    float sT[12] = {}, sT2[12] = {};
    #pragma unroll
    for (int j = 0; j < 4; j++) {
        #pragma unroll
        for (int i = 0; i < 12; i++) {
            float s = 0.f;
            #pragma unroll
            for (int h = 0; h < 12; h++) s = fmaf(th_s[h * 12 + i], p[h][j], s);
            sc[i][j] = s;
            sT[i] += s;
            sT2[i] = fmaf(s, s, sT2[i]);
        }
    }
    reduce12(sT,  l_sum,  red, t, false);
    reduce12(sT2, l_sum2, red, t, false);
    if (t < 12) {
        float mean = l_sum[t] * (1.0f / 1024.0f);
        float var  = l_sum2[t] * (1.0f / 1024.0f) - mean * mean;
        l_mean[t] = mean;
        l_rstd[t] = rsqrtf(var + 1e-6f);
    }
    __syncthreads();

    // ---- LayerNorm + write A (bf16) in place over P ----
    float4 s4 = *(const float4*)(ln_scale + k0);
    float4 b4 = *(const float4*)(ln_bias + k0);
    #pragma unroll
    for (int i = 0; i < 12; i++) {
        float mm = l_mean[i], rs = l_rstd[i];
        ushort4 o;
        o.x = f2bf(fmaf((sc[i][0] - mm) * rs, s4.x, b4.x));
        o.y = f2bf(fmaf((sc[i][1] - mm) * rs, s4.y, b4.y));
        o.z = f2bf(fmaf((sc[i][2] - mm) * rs, s4.z, b4.z));
        o.w = f2bf(fmaf((sc[i][3] - mm) * rs, s4.w, b4.w));
        *(ushort4*)(P + (((size_t)(b * NH + i)) * NSEQ + q) * NSEQ + k0) = o;
    }
}

// ---------------------------------------------------------------------------
// Kernel 3: out[b][k][i*64+d] = sum_q A[b][i][q][k] * V[b][i][q][d]
// 64(k) x 64(d) tile per block, K-loop over q in chunks of 32.
// ---------------------------------------------------------------------------
__global__ __launch_bounds__(256) void av_gemm(
    const unsigned short* __restrict__ A, const unsigned short* __restrict__ V,
    float* __restrict__ out)
{
    const int b  = blockIdx.z;
    const int i  = blockIdx.y;
    const int kk0 = blockIdx.x * 64;
    const int t  = threadIdx.x;
    const int tx = t & 15, ty = t >> 4;

    __shared__ float As[32][65];   // [qq][k_local]
    __shared__ float Vs[32][65];   // [qq][d]

    float acc[4][4] = {};
    const unsigned short* Ai = A + ((size_t)b * NH + i) * NSEQ * NSEQ;
    const unsigned short* Vi = V + ((size_t)b * NH + i) * NSEQ * DH;

    const int lq = t >> 3, lc = (t & 7) * 8;

    for (int q0 = 0; q0 < NSEQ; q0 += 32) {
        const unsigned short* ap = Ai + (size_t)(q0 + lq) * NSEQ + kk0 + lc;
        ushort4 a0 = *(const ushort4*)ap;
        ushort4 a1 = *(const ushort4*)(ap + 4);
        const unsigned short* vp = Vi + (size_t)(q0 + lq) * DH + lc;
        ushort4 v0 = *(const ushort4*)vp;
        ushort4 v1 = *(const ushort4*)(vp + 4);
        __syncthreads();
        As[lq][lc + 0] = bf2f(a0.x); As[lq][lc + 1] = bf2f(a0.y);
        As[lq][lc + 2] = bf2f(a0.z); As[lq][lc + 3] = bf2f(a0.w);
        As[lq][lc + 4] = bf2f(a1.x); As[lq][lc + 5] = bf2f(a1.y);
        As[lq][lc + 6] = bf2f(a1.z); As[lq][lc + 7] = bf2f(a1.w);
        Vs[lq][lc + 0] = bf2f(v0.x); Vs[lq][lc + 1] = bf2f(v0.y);
        Vs[lq][lc + 2] = bf2f(v0.z); Vs[lq][lc + 3] = bf2f(v0.w);
        Vs[lq][lc + 4] = bf2f(v1.x); Vs[lq][lc + 5] = bf2f(v1.y);
        Vs[lq][lc + 6] = bf2f(v1.z); Vs[lq][lc + 7] = bf2f(v1.w);
        __syncthreads();
        #pragma unroll
        for (int qq = 0; qq < 32; qq++) {
            float a0f = As[qq][ty * 4 + 0], a1f = As[qq][ty * 4 + 1];
            float a2f = As[qq][ty * 4 + 2], a3f = As[qq][ty * 4 + 3];
            float b0f = Vs[qq][tx * 4 + 0], b1f = Vs[qq][tx * 4 + 1];
            float b2f = Vs[qq][tx * 4 + 2], b3f = Vs[qq][tx * 4 + 3];
            acc[0][0] = fmaf(a0f, b0f, acc[0][0]); acc[0][1] = fmaf(a0f, b1f, acc[0][1]);
            acc[0][2] = fmaf(a0f, b2f, acc[0][2]); acc[0][3] = fmaf(a0f, b3f, acc[0][3]);
            acc[1][0] = fmaf(a1f, b0f, acc[1][0]); acc[1][1] = fmaf(a1f, b1f, acc[1][1]);
            acc[1][2] = fmaf(a1f, b2f, acc[1][2]); acc[1][3] = fmaf(a1f, b3f, acc[1][3]);
            acc[2][0] = fmaf(a2f, b0f, acc[2][0]); acc[2][1] = fmaf(a2f, b1f, acc[2][1]);
            acc[2][2] = fmaf(a2f, b2f, acc[2][2]); acc[2][3] = fmaf(a2f, b3f, acc[2][3]);
            acc[3][0] = fmaf(a3f, b0f, acc[3][0]); acc[3][1] = fmaf(a3f, b1f, acc[3][1]);
            acc[3][2] = fmaf(a3f, b2f, acc[3][2]); acc[3][3] = fmaf(a3f, b3f, acc[3][3]);
        }
    }

    #pragma unroll
    for (int ii = 0; ii < 4; ii++) {
        int k = kk0 + ty * 4 + ii;
        float4 o = make_float4(acc[ii][0], acc[ii][1], acc[ii][2], acc[ii][3]);
        *(float4*)(out + ((size_t)b * NSEQ + k) * DMODEL + i * DH + tx * 4) = o;
    }
}

extern "C" void kernel_launch(void* const* d_in, const int* in_sizes, int n_in,
                              void* d_out, int out_size, void* d_ws, size_t ws_size,
                              hipStream_t stream) {
    const float* x     = (const float*)d_in[0];
    const float* Wq    = (const float*)d_in[1];
    const float* Wk    = (const float*)d_in[2];
    const float* Wv    = (const float*)d_in[3];
    const float* theta = (const float*)d_in[4];
    const float* ln_s  = (const float*)d_in[5];
    const float* ln_b  = (const float*)d_in[6];
    float* out = (float*)d_out;

    char* ws = (char*)d_ws;
    const size_t qsz = (size_t)NB * NSEQ * DMODEL * sizeof(unsigned short); // 6.29 MB
    unsigned short* Q = (unsigned short*)(ws);
    unsigned short* K = (unsigned short*)(ws + qsz);
    unsigned short* V = (unsigned short*)(ws + 2 * qsz);
    unsigned short* P = (unsigned short*)(ws + 3 * qsz);  // 100.7 MB, becomes A in-place

    qkv_gemm<<<dim3(NB * NSEQ / 64, DMODEL / 64, 3), 256, 0, stream>>>(
        x, Wq, Wk, Wv, Q, K, V);
    score_gemm<<<dim3(NSEQ / 128, NSEQ / 128, NB * NH), 256, 0, stream>>>(Q, K, P);
    mix_ln<<<dim3(NSEQ, NB), 256, 0, stream>>>(P, theta, ln_s, ln_b);
    av_gemm<<<dim3(NSEQ / 64, NH, NB), 256, 0, stream>>>(P, V, out);
}

// Round 3
// 520.005 us; speedup vs baseline: 2.2657x; 1.3370x over previous
//
#include <hip/hip_runtime.h>

#define NB    4
#define NSEQ  1024
#define DMODEL 768
#define NH    12
#define DH    64

typedef __bf16 bf16x8 __attribute__((ext_vector_type(8)));
typedef float  floatx4 __attribute__((ext_vector_type(4)));

static __device__ __forceinline__ float bf2f(unsigned short u) {
    return __uint_as_float(((unsigned)u) << 16);
}
static __device__ __forceinline__ unsigned short f2bf(float f) {
    unsigned u = __float_as_uint(f);
    u += 0x7FFFu + ((u >> 16) & 1u);   // round-to-nearest-even
    return (unsigned short)(u >> 16);
}

// ---------------------------------------------------------------------------
// cast_x: x fp32 [4096*768] -> bf16
// ---------------------------------------------------------------------------
__global__ __launch_bounds__(256) void cast_x(
    const float* __restrict__ x, unsigned short* __restrict__ xb)
{
    const int g = blockIdx.x * 256 + threadIdx.x;
    const size_t base = (size_t)g * 8;
    float4 a = *(const float4*)(x + base);
    float4 b = *(const float4*)(x + base + 4);
    unsigned short o[8];
    o[0] = f2bf(a.x); o[1] = f2bf(a.y); o[2] = f2bf(a.z); o[3] = f2bf(a.w);
    o[4] = f2bf(b.x); o[5] = f2bf(b.y); o[6] = f2bf(b.z); o[7] = f2bf(b.w);
    *(uint4*)(xb + base) = *(uint4*)o;
}

// ---------------------------------------------------------------------------
// tr_w: W fp32 [768 k][768 c] -> Wt bf16 [768 c][768 k]  (z selects Wq/Wk/Wv)
// 64x64 tile transpose through LDS.
// ---------------------------------------------------------------------------
__global__ __launch_bounds__(256) void tr_w(
    const float* __restrict__ Wq, const float* __restrict__ Wk,
    const float* __restrict__ Wv, unsigned short* __restrict__ Wt)
{
    const int z  = blockIdx.z;
    const float* __restrict__ W = (z == 0) ? Wq : (z == 1) ? Wk : Wv;
    const int c0 = blockIdx.x * 64;
    const int k0 = blockIdx.y * 64;
    const int t  = threadIdx.x;

    __shared__ float ls[64][65];

    const int lr = t >> 2;
    #pragma unroll
    for (int j = 0; j < 4; j++) {
        int col = (t & 3) * 16 + j * 4;
        float4 v = *(const float4*)(W + (size_t)(k0 + lr) * DMODEL + c0 + col);
        ls[lr][col + 0] = v.x; ls[lr][col + 1] = v.y;
        ls[lr][col + 2] = v.z; ls[lr][col + 3] = v.w;
    }
    __syncthreads();
    const int lc = t >> 2;
    #pragma unroll
    for (int j = 0; j < 4; j++) {
        int kb = (t & 3) * 16 + j * 4;
        ushort4 o;
        o.x = f2bf(ls[kb + 0][lc]); o.y = f2bf(ls[kb + 1][lc]);
        o.z = f2bf(ls[kb + 2][lc]); o.w = f2bf(ls[kb + 3][lc]);
        *(ushort4*)(Wt + (size_t)z * DMODEL * DMODEL + (size_t)(c0 + lc) * DMODEL + k0 + kb) = o;
    }
}

// ---------------------------------------------------------------------------
// qkv_mfma: C[4096][768] = xb @ Wt[z]^T via MFMA bf16, 128x128 tile / block.
//   z=0: Q natural [b n][768], *0.125
//   z=1: K[b][h][n][d],  z=2: V[b][h][n][d]
// ---------------------------------------------------------------------------
__global__ __launch_bounds__(256) void qkv_mfma(
    const unsigned short* __restrict__ xb, const unsigned short* __restrict__ Wt,
    unsigned short* __restrict__ Q, unsigned short* __restrict__ K,
    unsigned short* __restrict__ V)
{
    const int z  = blockIdx.z;
    const int r0 = blockIdx.x * 128;
    const int c0 = blockIdx.y * 128;
    const int t    = threadIdx.x;
    const int wave = t >> 6, lane = t & 63;
    const int m = lane & 15, g = lane >> 4;

    const unsigned short* __restrict__ B = Wt + (size_t)z * DMODEL * DMODEL;

    __shared__ __align__(16) char sm[36864];
    unsigned short (*As)[40] = (unsigned short(*)[40])sm;            // 128x40
    unsigned short (*Bs)[40] = (unsigned short(*)[40])(sm + 10240);  // 128x40
    unsigned short (*Po)[136] = (unsigned short(*)[136])sm;          // epilogue

    const int wq = (wave >> 1) * 64, wc = (wave & 1) * 64;

    floatx4 acc[4][4] = {};

    for (int k0 = 0; k0 < DMODEL; k0 += 32) {
        uint4 av[2], bv[2];
        #pragma unroll
        for (int i = 0; i < 2; i++) {
            int ci = t + i * 256;          // 0..511
            int row = ci >> 2, off = (ci & 3) * 8;
            av[i] = *(const uint4*)(xb + (size_t)(r0 + row) * DMODEL + k0 + off);
            bv[i] = *(const uint4*)(B  + (size_t)(c0 + row) * DMODEL + k0 + off);
        }
        __syncthreads();
        #pragma unroll
        for (int i = 0; i < 2; i++) {
            int ci = t + i * 256;
            int row = ci >> 2, off = (ci & 3) * 8;
            *(uint4*)&As[row][off] = av[i];
            *(uint4*)&Bs[row][off] = bv[i];
        }
        __syncthreads();

        bf16x8 af[4], bf[4];
        #pragma unroll
        for (int mt = 0; mt < 4; mt++)
            af[mt] = *(const bf16x8*)&As[wq + mt * 16 + m][g * 8];
        #pragma unroll
        for (int nt = 0; nt < 4; nt++)
            bf[nt] = *(const bf16x8*)&Bs[wc + nt * 16 + m][g * 8];
        #pragma unroll
        for (int mt = 0; mt < 4; mt++)
            #pragma unroll
            for (int nt = 0; nt < 4; nt++)
                acc[mt][nt] = __builtin_amdgcn_mfma_f32_16x16x32_bf16(
                    af[mt], bf[nt], acc[mt][nt], 0, 0, 0);
    }

    __syncthreads();   // done with As/Bs; reuse as Po
    const float scale = (z == 0) ? 0.125f : 1.0f;
    #pragma unroll
    for (int mt = 0; mt < 4; mt++) {
        #pragma unroll
        for (int nt = 0; nt < 4; nt++) {
            int rloc = wq + mt * 16 + g * 4;
            int cloc = wc + nt * 16 + m;
            #pragma unroll
            for (int r = 0; r < 4; r++)
                Po[rloc + r][cloc] = f2bf(acc[mt][nt][r] * scale);
        }
    }
    __syncthreads();

    #pragma unroll
    for (int i = 0; i < 8; i++) {
        int ci = t + i * 256;             // 0..2047
        int row = ci >> 4, off = (ci & 15) * 8;
        uint4 val = *(uint4*)&Po[row][off];
        if (z == 0) {
            *(uint4*)(Q + (size_t)(r0 + row) * DMODEL + c0 + off) = val;
        } else {
            unsigned short* P = (z == 1) ? K : V;
            int rr = r0 + row;
            int b = rr >> 10, n = rr & 1023;
            int cc = c0 + off;
            int h = cc >> 6, d = cc & 63;
            *(uint4*)(P + (((size_t)b * NH + h) * NSEQ + n) * DH + d) = val;
        }
    }
}

// ---------------------------------------------------------------------------
// score_gemm: per (b,h): S = (Q_h/8) . K_h^T via MFMA, 128x128 tile.
// Writes P = exp(S) unnormalized, bf16, P[b][h][q][k].
// ---------------------------------------------------------------------------
__global__ __launch_bounds__(256) void score_gemm(
    const unsigned short* __restrict__ Q, const unsigned short* __restrict__ K,
    unsigned short* __restrict__ P)
{
    const int bh = blockIdx.z;        // b*12+h
    const int b  = bh / NH, h = bh % NH;
    const int q0 = blockIdx.x * 128;
    const int k0 = blockIdx.y * 128;
    const int t    = threadIdx.x;
    const int wave = t >> 6, lane = t & 63;

    __shared__ __align__(16) char sm[36864];
    unsigned short (*Qs)[72] = (unsigned short(*)[72])sm;            // 128 x 72
    unsigned short (*Ks)[72] = (unsigned short(*)[72])(sm + 18432);  // 128 x 72
    unsigned short (*Po)[136] = (unsigned short(*)[136])sm;          // epilogue reuse

    #pragma unroll
    for (int i = 0; i < 4; i++) {
        int c = t + i * 256;              // 0..1023
        int row = c >> 3, off = (c & 7) * 8;
        uint4 qa = *(const uint4*)(Q + ((size_t)(b * NSEQ + q0 + row)) * DMODEL + h * DH + off);
        uint4 ka = *(const uint4*)(K + (((size_t)bh) * NSEQ + (k0 + row)) * DH + off);
        *(uint4*)&Qs[row][off] = qa;
        *(uint4*)&Ks[row][off] = ka;
    }
    __syncthreads();

    const int wq = (wave >> 1) * 64, wk2 = (wave & 1) * 64;
    const int m = lane & 15, g = lane >> 4;

    floatx4 acc[4][4] = {};
    #pragma unroll
    for (int ds = 0; ds < 2; ds++) {
        const int dd = ds * 32 + g * 8;
        bf16x8 af[4], bf[4];
        #pragma unroll
        for (int mt = 0; mt < 4; mt++)
            af[mt] = *(const bf16x8*)&Qs[wq + mt * 16 + m][dd];
        #pragma unroll
        for (int nt = 0; nt < 4; nt++)
            bf[nt] = *(const bf16x8*)&Ks[wk2 + nt * 16 + m][dd];
        #pragma unroll
        for (int mt = 0; mt < 4; mt++)
            #pragma unroll
            for (int nt = 0; nt < 4; nt++)
                acc[mt][nt] = __builtin_amdgcn_mfma_f32_16x16x32_bf16(
                    af[mt], bf[nt], acc[mt][nt], 0, 0, 0);
    }

    __syncthreads();   // done with Qs/Ks; reuse as Po
    #pragma unroll
    for (int mt = 0; mt < 4; mt++) {
        #pragma unroll
        for (int nt = 0; nt < 4; nt++) {
            int qloc = wq + mt * 16 + g * 4;
            int kloc = wk2 + nt * 16 + m;
            #pragma unroll
            for (int r = 0; r < 4; r++)
                Po[qloc + r][kloc] = f2bf(__expf(acc[mt][nt][r]));
        }
    }
    __syncthreads();

    #pragma unroll
    for (int i = 0; i < 8; i++) {
        int c = t + i * 256;              // 0..2047
        int row = c >> 4, off = (c & 15) * 8;
        *(uint4*)(P + (((size_t)bh * NSEQ) + q0 + row) * NSEQ + k0 + off) =
            *(uint4*)&Po[row][off];
    }
}

// ---------------------------------------------------------------------------
// block-wide reduction of 12 per-thread values (max or sum), result in out12
// ---------------------------------------------------------------------------
static __device__ __forceinline__ void reduce12(
    const float* v, float* out12, float* red, int t, bool is_max)
{
    const int lane = t & 63, w = t >> 6;
    #pragma unroll
    for (int h = 0; h < 12; h++) {
        float x = v[h];
        #pragma unroll
        for (int off = 32; off > 0; off >>= 1) {
            float o = __shfl_down(x, off, 64);
            x = is_max ? fmaxf(x, o) : (x + o);
        }
        if (lane == 0) red[w * 12 + h] = x;
    }
    __syncthreads();
    if (t < 12) {
        float x = red[t];
        #pragma unroll
        for (int w2 = 1; w2 < 4; w2++) {
            float o = red[w2 * 12 + t];
            x = is_max ? fmaxf(x, o) : (x + o);
        }
        out12[t] = x;
    }
    __syncthreads();
}

// ---------------------------------------------------------------------------
// mix_ln: per (b,q): softmax denominators, theta mix, LayerNorm over k,
// write A bf16 IN PLACE over P.
// ---------------------------------------------------------------------------
__global__ __launch_bounds__(256) void mix_ln(
    unsigned short* __restrict__ P, const float* __restrict__ theta,
    const float* __restrict__ ln_scale, const float* __restrict__ ln_bias)
{
    const int q = blockIdx.x;
    const int b = blockIdx.y;
    const int t = threadIdx.x;

    __shared__ float th_s[144];
    __shared__ float red[48];
    __shared__ float l_l[12], l_sum[12], l_sum2[12], l_mean[12], l_rstd[12];

    const int k0 = t * 4;
    float p[12][4];
    float r12[12];

    #pragma unroll
    for (int h = 0; h < NH; h++) {
        ushort4 u = *(const ushort4*)(P + (((size_t)(b * NH + h)) * NSEQ + q) * NSEQ + k0);
        p[h][0] = bf2f(u.x); p[h][1] = bf2f(u.y);
        p[h][2] = bf2f(u.z); p[h][3] = bf2f(u.w);
        r12[h] = (p[h][0] + p[h][1]) + (p[h][2] + p[h][3]);
    }
    reduce12(r12, l_l, red, t, false);

    if (t < 144) th_s[t] = theta[t] * (1.0f / l_l[t / 12]);
    __syncthreads();

    float sc[12][4];
    float sT[12] = {}, sT2[12] = {};
    #pragma unroll
    for (int j = 0; j < 4; j++) {
        #pragma unroll
        for (int i = 0; i < 12; i++) {
            float s = 0.f;
            #pragma unroll
            for (int h = 0; h < 12; h++) s = fmaf(th_s[h * 12 + i], p[h][j], s);
            sc[i][j] = s;
            sT[i] += s;
            sT2[i] = fmaf(s, s, sT2[i]);
        }
    }
    reduce12(sT,  l_sum,  red, t, false);
    reduce12(sT2, l_sum2, red, t, false);
    if (t < 12) {
        float mean = l_sum[t] * (1.0f / 1024.0f);
        float var  = l_sum2[t] * (1.0f / 1024.0f) - mean * mean;
        l_mean[t] = mean;
        l_rstd[t] = rsqrtf(var + 1e-6f);
    }
    __syncthreads();

    float4 s4 = *(const float4*)(ln_scale + k0);
    float4 b4 = *(const float4*)(ln_bias + k0);
    #pragma unroll
    for (int i = 0; i < 12; i++) {
        float mm = l_mean[i], rs = l_rstd[i];
        ushort4 o;
        o.x = f2bf(fmaf((sc[i][0] - mm) * rs, s4.x, b4.x));
        o.y = f2bf(fmaf((sc[i][1] - mm) * rs, s4.y, b4.y));
        o.z = f2bf(fmaf((sc[i][2] - mm) * rs, s4.z, b4.z));
        o.w = f2bf(fmaf((sc[i][3] - mm) * rs, s4.w, b4.w));
        *(ushort4*)(P + (((size_t)(b * NH + i)) * NSEQ + q) * NSEQ + k0) = o;
    }
}

// ---------------------------------------------------------------------------
// av_gemm: out[b][k][i*64+d] = sum_q A[b][i][q][k] * V[b][i][q][d]
// ---------------------------------------------------------------------------
__global__ __launch_bounds__(256) void av_gemm(
    const unsigned short* __restrict__ A, const unsigned short* __restrict__ V,
    float* __restrict__ out)
{
    const int b  = blockIdx.z;
    const int i  = blockIdx.y;
    const int kk0 = blockIdx.x * 64;
    const int t  = threadIdx.x;
    const int tx = t & 15, ty = t >> 4;

    __shared__ float As[32][65];
    __shared__ float Vs[32][65];

    float acc[4][4] = {};
    const unsigned short* Ai = A + ((size_t)b * NH + i) * NSEQ * NSEQ;
    const unsigned short* Vi = V + ((size_t)b * NH + i) * NSEQ * DH;

    const int lq = t >> 3, lc = (t & 7) * 8;

    for (int q0 = 0; q0 < NSEQ; q0 += 32) {
        const unsigned short* ap = Ai + (size_t)(q0 + lq) * NSEQ + kk0 + lc;
        ushort4 a0 = *(const ushort4*)ap;
        ushort4 a1 = *(const ushort4*)(ap + 4);
        const unsigned short* vp = Vi + (size_t)(q0 + lq) * DH + lc;
        ushort4 v0 = *(const ushort4*)vp;
        ushort4 v1 = *(const ushort4*)(vp + 4);
        __syncthreads();
        As[lq][lc + 0] = bf2f(a0.x); As[lq][lc + 1] = bf2f(a0.y);
        As[lq][lc + 2] = bf2f(a0.z); As[lq][lc + 3] = bf2f(a0.w);
        As[lq][lc + 4] = bf2f(a1.x); As[lq][lc + 5] = bf2f(a1.y);
        As[lq][lc + 6] = bf2f(a1.z); As[lq][lc + 7] = bf2f(a1.w);
        Vs[lq][lc + 0] = bf2f(v0.x); Vs[lq][lc + 1] = bf2f(v0.y);
        Vs[lq][lc + 2] = bf2f(v0.z); Vs[lq][lc + 3] = bf2f(v0.w);
        Vs[lq][lc + 4] = bf2f(v1.x); Vs[lq][lc + 5] = bf2f(v1.y);
        Vs[lq][lc + 6] = bf2f(v1.z); Vs[lq][lc + 7] = bf2f(v1.w);
        __syncthreads();
        #pragma unroll
        for (int qq = 0; qq < 32; qq++) {
            float a0f = As[qq][ty * 4 + 0], a1f = As[qq][ty * 4 + 1];
            float a2f = As[qq][ty * 4 + 2], a3f = As[qq][ty * 4 + 3];
            float b0f = Vs[qq][tx * 4 + 0], b1f = Vs[qq][tx * 4 + 1];
            float b2f = Vs[qq][tx * 4 + 2], b3f = Vs[qq][tx * 4 + 3];
            acc[0][0] = fmaf(a0f, b0f, acc[0][0]); acc[0][1] = fmaf(a0f, b1f, acc[0][1]);
            acc[0][2] = fmaf(a0f, b2f, acc[0][2]); acc[0][3] = fmaf(a0f, b3f, acc[0][3]);
            acc[1][0] = fmaf(a1f, b0f, acc[1][0]); acc[1][1] = fmaf(a1f, b1f, acc[1][1]);
            acc[1][2] = fmaf(a1f, b2f, acc[1][2]); acc[1][3] = fmaf(a1f, b3f, acc[1][3]);
            acc[2][0] = fmaf(a2f, b0f, acc[2][0]); acc[2][1] = fmaf(a2f, b1f, acc[2][1]);
            acc[2][2] = fmaf(a2f, b2f, acc[2][2]); acc[2][3] = fmaf(a2f, b3f, acc[2][3]);
            acc[3][0] = fmaf(a3f, b0f, acc[3][0]); acc[3][1] = fmaf(a3f, b1f, acc[3][1]);
            acc[3][2] = fmaf(a3f, b2f, acc[3][2]); acc[3][3] = fmaf(a3f, b3f, acc[3][3]);
        }
    }

    #pragma unroll
    for (int ii = 0; ii < 4; ii++) {
        int k = kk0 + ty * 4 + ii;
        float4 o = make_float4(acc[ii][0], acc[ii][1], acc[ii][2], acc[ii][3]);
        *(float4*)(out + ((size_t)b * NSEQ + k) * DMODEL + i * DH + tx * 4) = o;
    }
}

extern "C" void kernel_launch(void* const* d_in, const int* in_sizes, int n_in,
                              void* d_out, int out_size, void* d_ws, size_t ws_size,
                              hipStream_t stream) {
    const float* x     = (const float*)d_in[0];
    const float* Wq    = (const float*)d_in[1];
    const float* Wk    = (const float*)d_in[2];
    const float* Wv    = (const float*)d_in[3];
    const float* theta = (const float*)d_in[4];
    const float* ln_s  = (const float*)d_in[5];
    const float* ln_b  = (const float*)d_in[6];
    float* out = (float*)d_out;

    char* ws = (char*)d_ws;
    const size_t qsz = (size_t)NB * NSEQ * DMODEL * sizeof(unsigned short); // 6.29 MB
    unsigned short* Q = (unsigned short*)(ws);
    unsigned short* K = (unsigned short*)(ws + qsz);
    unsigned short* V = (unsigned short*)(ws + 2 * qsz);
    unsigned short* P = (unsigned short*)(ws + 3 * qsz);  // 100.7 MB, becomes A in-place
    // xb/Wt live inside the (not yet written) P region: dead before score_gemm
    unsigned short* xb = P;
    unsigned short* Wt = P + (size_t)NB * NSEQ * DMODEL;  // 3 x 768 x 768 bf16

    cast_x<<<dim3(NB * NSEQ * DMODEL / 2048), 256, 0, stream>>>(x, xb);
    tr_w<<<dim3(12, 12, 3), 256, 0, stream>>>(Wq, Wk, Wv, Wt);
    qkv_mfma<<<dim3(NB * NSEQ / 128, DMODEL / 128, 3), 256, 0, stream>>>(
        xb, Wt, Q, K, V);
    score_gemm<<<dim3(NSEQ / 128, NSEQ / 128, NB * NH), 256, 0, stream>>>(Q, K, P);
    mix_ln<<<dim3(NSEQ, NB), 256, 0, stream>>>(P, theta, ln_s, ln_b);
    av_gemm<<<dim3(NSEQ / 64, NH, NB), 256, 0, stream>>>(P, V, out);
}

// Round 4
// 453.278 us; speedup vs baseline: 2.5993x; 1.1472x over previous
//
#include <hip/hip_runtime.h>

#define NB    4
#define NSEQ  1024
#define DMODEL 768
#define NH    12
#define DH    64

typedef __bf16 bf16x8 __attribute__((ext_vector_type(8)));
typedef float  floatx4 __attribute__((ext_vector_type(4)));
typedef unsigned int u32;

static __device__ __forceinline__ float bf2f(unsigned short u) {
    return __uint_as_float(((unsigned)u) << 16);
}
static __device__ __forceinline__ unsigned short f2bf(float f) {
    unsigned u = __float_as_uint(f);
    u += 0x7FFFu + ((u >> 16) & 1u);   // round-to-nearest-even
    return (unsigned short)(u >> 16);
}

// ---------------------------------------------------------------------------
// cast_x: x fp32 [4096*768] -> bf16
// ---------------------------------------------------------------------------
__global__ __launch_bounds__(256) void cast_x(
    const float* __restrict__ x, unsigned short* __restrict__ xb)
{
    const int g = blockIdx.x * 256 + threadIdx.x;
    const size_t base = (size_t)g * 8;
    float4 a = *(const float4*)(x + base);
    float4 b = *(const float4*)(x + base + 4);
    unsigned short o[8];
    o[0] = f2bf(a.x); o[1] = f2bf(a.y); o[2] = f2bf(a.z); o[3] = f2bf(a.w);
    o[4] = f2bf(b.x); o[5] = f2bf(b.y); o[6] = f2bf(b.z); o[7] = f2bf(b.w);
    *(uint4*)(xb + base) = *(uint4*)o;
}

// ---------------------------------------------------------------------------
// tr_w: W fp32 [768 k][768 c] -> Wt bf16 [768 c][768 k]  (z selects Wq/Wk/Wv)
// ---------------------------------------------------------------------------
__global__ __launch_bounds__(256) void tr_w(
    const float* __restrict__ Wq, const float* __restrict__ Wk,
    const float* __restrict__ Wv, unsigned short* __restrict__ Wt)
{
    const int z  = blockIdx.z;
    const float* __restrict__ W = (z == 0) ? Wq : (z == 1) ? Wk : Wv;
    const int c0 = blockIdx.x * 64;
    const int k0 = blockIdx.y * 64;
    const int t  = threadIdx.x;

    __shared__ float ls[64][65];

    const int lr = t >> 2;
    #pragma unroll
    for (int j = 0; j < 4; j++) {
        int col = (t & 3) * 16 + j * 4;
        float4 v = *(const float4*)(W + (size_t)(k0 + lr) * DMODEL + c0 + col);
        ls[lr][col + 0] = v.x; ls[lr][col + 1] = v.y;
        ls[lr][col + 2] = v.z; ls[lr][col + 3] = v.w;
    }
    __syncthreads();
    const int lc = t >> 2;
    #pragma unroll
    for (int j = 0; j < 4; j++) {
        int kb = (t & 3) * 16 + j * 4;
        ushort4 o;
        o.x = f2bf(ls[kb + 0][lc]); o.y = f2bf(ls[kb + 1][lc]);
        o.z = f2bf(ls[kb + 2][lc]); o.w = f2bf(ls[kb + 3][lc]);
        *(ushort4*)(Wt + (size_t)z * DMODEL * DMODEL + (size_t)(c0 + lc) * DMODEL + k0 + kb) = o;
    }
}

// ---------------------------------------------------------------------------
// qkv_mfma: C[4096][768] = xb @ Wt[z]^T via MFMA bf16, 128x128 tile / block.
// ---------------------------------------------------------------------------
__global__ __launch_bounds__(256) void qkv_mfma(
    const unsigned short* __restrict__ xb, const unsigned short* __restrict__ Wt,
    unsigned short* __restrict__ Q, unsigned short* __restrict__ K,
    unsigned short* __restrict__ V)
{
    const int z  = blockIdx.z;
    const int r0 = blockIdx.x * 128;
    const int c0 = blockIdx.y * 128;
    const int t    = threadIdx.x;
    const int wave = t >> 6, lane = t & 63;
    const int m = lane & 15, g = lane >> 4;

    const unsigned short* __restrict__ B = Wt + (size_t)z * DMODEL * DMODEL;

    __shared__ __align__(16) char sm[36864];
    unsigned short (*As)[40] = (unsigned short(*)[40])sm;            // 128x40
    unsigned short (*Bs)[40] = (unsigned short(*)[40])(sm + 10240);  // 128x40
    unsigned short (*Po)[136] = (unsigned short(*)[136])sm;          // epilogue

    const int wq = (wave >> 1) * 64, wc = (wave & 1) * 64;

    floatx4 acc[4][4] = {};

    for (int k0 = 0; k0 < DMODEL; k0 += 32) {
        uint4 av[2], bv[2];
        #pragma unroll
        for (int i = 0; i < 2; i++) {
            int ci = t + i * 256;          // 0..511
            int row = ci >> 2, off = (ci & 3) * 8;
            av[i] = *(const uint4*)(xb + (size_t)(r0 + row) * DMODEL + k0 + off);
            bv[i] = *(const uint4*)(B  + (size_t)(c0 + row) * DMODEL + k0 + off);
        }
        __syncthreads();
        #pragma unroll
        for (int i = 0; i < 2; i++) {
            int ci = t + i * 256;
            int row = ci >> 2, off = (ci & 3) * 8;
            *(uint4*)&As[row][off] = av[i];
            *(uint4*)&Bs[row][off] = bv[i];
        }
        __syncthreads();

        bf16x8 af[4], bf[4];
        #pragma unroll
        for (int mt = 0; mt < 4; mt++)
            af[mt] = *(const bf16x8*)&As[wq + mt * 16 + m][g * 8];
        #pragma unroll
        for (int nt = 0; nt < 4; nt++)
            bf[nt] = *(const bf16x8*)&Bs[wc + nt * 16 + m][g * 8];
        #pragma unroll
        for (int mt = 0; mt < 4; mt++)
            #pragma unroll
            for (int nt = 0; nt < 4; nt++)
                acc[mt][nt] = __builtin_amdgcn_mfma_f32_16x16x32_bf16(
                    af[mt], bf[nt], acc[mt][nt], 0, 0, 0);
    }

    __syncthreads();
    const float scale = (z == 0) ? 0.125f : 1.0f;
    #pragma unroll
    for (int mt = 0; mt < 4; mt++) {
        #pragma unroll
        for (int nt = 0; nt < 4; nt++) {
            int rloc = wq + mt * 16 + g * 4;
            int cloc = wc + nt * 16 + m;
            #pragma unroll
            for (int r = 0; r < 4; r++)
                Po[rloc + r][cloc] = f2bf(acc[mt][nt][r] * scale);
        }
    }
    __syncthreads();

    #pragma unroll
    for (int i = 0; i < 8; i++) {
        int ci = t + i * 256;             // 0..2047
        int row = ci >> 4, off = (ci & 15) * 8;
        uint4 val = *(uint4*)&Po[row][off];
        if (z == 0) {
            *(uint4*)(Q + (size_t)(r0 + row) * DMODEL + c0 + off) = val;
        } else {
            unsigned short* P = (z == 1) ? K : V;
            int rr = r0 + row;
            int b = rr >> 10, n = rr & 1023;
            int cc = c0 + off;
            int h = cc >> 6, d = cc & 63;
            *(uint4*)(P + (((size_t)b * NH + h) * NSEQ + n) * DH + d) = val;
        }
    }
}

// ---------------------------------------------------------------------------
// score_gemm: per (b,h): S = (Q_h/8) . K_h^T via MFMA, 128x128 tile.
// Writes P = exp(S) unnormalized, bf16, P[b][h][q][k].
// ---------------------------------------------------------------------------
__global__ __launch_bounds__(256) void score_gemm(
    const unsigned short* __restrict__ Q, const unsigned short* __restrict__ K,
    unsigned short* __restrict__ P)
{
    const int bh = blockIdx.z;        // b*12+h
    const int b  = bh / NH, h = bh % NH;
    const int q0 = blockIdx.x * 128;
    const int k0 = blockIdx.y * 128;
    const int t    = threadIdx.x;
    const int wave = t >> 6, lane = t & 63;

    __shared__ __align__(16) char sm[36864];
    unsigned short (*Qs)[72] = (unsigned short(*)[72])sm;            // 128 x 72
    unsigned short (*Ks)[72] = (unsigned short(*)[72])(sm + 18432);  // 128 x 72
    unsigned short (*Po)[136] = (unsigned short(*)[136])sm;          // epilogue reuse

    #pragma unroll
    for (int i = 0; i < 4; i++) {
        int c = t + i * 256;              // 0..1023
        int row = c >> 3, off = (c & 7) * 8;
        uint4 qa = *(const uint4*)(Q + ((size_t)(b * NSEQ + q0 + row)) * DMODEL + h * DH + off);
        uint4 ka = *(const uint4*)(K + (((size_t)bh) * NSEQ + (k0 + row)) * DH + off);
        *(uint4*)&Qs[row][off] = qa;
        *(uint4*)&Ks[row][off] = ka;
    }
    __syncthreads();

    const int wq = (wave >> 1) * 64, wk2 = (wave & 1) * 64;
    const int m = lane & 15, g = lane >> 4;

    floatx4 acc[4][4] = {};
    #pragma unroll
    for (int ds = 0; ds < 2; ds++) {
        const int dd = ds * 32 + g * 8;
        bf16x8 af[4], bf[4];
        #pragma unroll
        for (int mt = 0; mt < 4; mt++)
            af[mt] = *(const bf16x8*)&Qs[wq + mt * 16 + m][dd];
        #pragma unroll
        for (int nt = 0; nt < 4; nt++)
            bf[nt] = *(const bf16x8*)&Ks[wk2 + nt * 16 + m][dd];
        #pragma unroll
        for (int mt = 0; mt < 4; mt++)
            #pragma unroll
            for (int nt = 0; nt < 4; nt++)
                acc[mt][nt] = __builtin_amdgcn_mfma_f32_16x16x32_bf16(
                    af[mt], bf[nt], acc[mt][nt], 0, 0, 0);
    }

    __syncthreads();
    #pragma unroll
    for (int mt = 0; mt < 4; mt++) {
        #pragma unroll
        for (int nt = 0; nt < 4; nt++) {
            int qloc = wq + mt * 16 + g * 4;
            int kloc = wk2 + nt * 16 + m;
            #pragma unroll
            for (int r = 0; r < 4; r++)
                Po[qloc + r][kloc] = f2bf(__expf(acc[mt][nt][r]));
        }
    }
    __syncthreads();

    #pragma unroll
    for (int i = 0; i < 8; i++) {
        int c = t + i * 256;              // 0..2047
        int row = c >> 4, off = (c & 15) * 8;
        *(uint4*)(P + (((size_t)bh * NSEQ) + q0 + row) * NSEQ + k0 + off) =
            *(uint4*)&Po[row][off];
    }
}

// ---------------------------------------------------------------------------
// block-wide reduction of 12 per-thread values (max or sum), result in out12
// ---------------------------------------------------------------------------
static __device__ __forceinline__ void reduce12(
    const float* v, float* out12, float* red, int t, bool is_max)
{
    const int lane = t & 63, w = t >> 6;
    #pragma unroll
    for (int h = 0; h < 12; h++) {
        float x = v[h];
        #pragma unroll
        for (int off = 32; off > 0; off >>= 1) {
            float o = __shfl_down(x, off, 64);
            x = is_max ? fmaxf(x, o) : (x + o);
        }
        if (lane == 0) red[w * 12 + h] = x;
    }
    __syncthreads();
    if (t < 12) {
        float x = red[t];
        #pragma unroll
        for (int w2 = 1; w2 < 4; w2++) {
            float o = red[w2 * 12 + t];
            x = is_max ? fmaxf(x, o) : (x + o);
        }
        out12[t] = x;
    }
    __syncthreads();
}

// ---------------------------------------------------------------------------
// mix_ln v2: per (b,q). Raw P row (12 heads x 1024 k, bf16) parked in LDS.
// Two passes over LDS (stats, apply) recomputing the theta mix instead of
// caching it in registers -> low VGPR, higher occupancy. In-place overwrite:
// each thread reads/writes only its own k-columns {2t,2t+1,512+2t,512+2t+1}.
// ---------------------------------------------------------------------------
__global__ __launch_bounds__(256) void mix_ln(
    unsigned short* __restrict__ P, const float* __restrict__ theta,
    const float* __restrict__ ln_scale, const float* __restrict__ ln_bias)
{
    const int q = blockIdx.x;
    const int b = blockIdx.y;
    const int t = threadIdx.x;

    __shared__ __align__(16) unsigned short Praw[12][1024];   // 24 KB
    __shared__ float th_s[144];
    __shared__ float red[48];
    __shared__ float l_l[12], l_sum[12], l_sum2[12], l_mean[12], l_rstd[12];

    u32* Pw = (u32*)&Praw[0][0];       // 12 rows x 512 uints

    // ---- load (coalesced ushort4 per head) + row-sum contribution ----
    float r12[12];
    #pragma unroll
    for (int h = 0; h < NH; h++) {
        ushort4 u = *(const ushort4*)(P + (((size_t)(b * NH + h)) * NSEQ + q) * NSEQ + 4 * t);
        *(ushort4*)&Praw[h][4 * t] = u;
        r12[h] = (bf2f(u.x) + bf2f(u.y)) + (bf2f(u.z) + bf2f(u.w));
    }
    __syncthreads();
    reduce12(r12, l_l, red, t, false);

    if (t < 144) th_s[t] = theta[t] * (1.0f / l_l[t / 12]);
    __syncthreads();

    // ---- stats pass: recomputable mix, accumulate sum & sum^2 ----
    float sT[12] = {}, sT2[12] = {};
    #pragma unroll
    for (int jj = 0; jj < 2; jj++) {
        float p0[12], p1[12];
        #pragma unroll
        for (int h = 0; h < 12; h++) {
            u32 w = Pw[h * 512 + jj * 256 + t];
            p0[h] = __uint_as_float(w << 16);
            p1[h] = __uint_as_float(w & 0xffff0000u);
        }
        #pragma unroll
        for (int i = 0; i < 12; i++) {
            float s0 = 0.f, s1 = 0.f;
            #pragma unroll
            for (int h = 0; h < 12; h++) {
                float th = th_s[h * 12 + i];
                s0 = fmaf(th, p0[h], s0);
                s1 = fmaf(th, p1[h], s1);
            }
            sT[i]  += s0 + s1;
            sT2[i]  = fmaf(s0, s0, fmaf(s1, s1, sT2[i]));
        }
    }
    reduce12(sT,  l_sum,  red, t, false);
    reduce12(sT2, l_sum2, red, t, false);
    if (t < 12) {
        float mean = l_sum[t] * (1.0f / 1024.0f);
        float var  = l_sum2[t] * (1.0f / 1024.0f) - mean * mean;
        l_mean[t] = mean;
        l_rstd[t] = rsqrtf(var + 1e-6f);
    }
    __syncthreads();

    // ---- apply pass: recompute mix, LayerNorm, overwrite own columns ----
    #pragma unroll
    for (int jj = 0; jj < 2; jj++) {
        const int k0 = jj * 512 + 2 * t;
        float2 lsc = *(const float2*)(ln_scale + k0);
        float2 lbs = *(const float2*)(ln_bias + k0);
        float p0[12], p1[12];
        #pragma unroll
        for (int h = 0; h < 12; h++) {
            u32 w = Pw[h * 512 + jj * 256 + t];
            p0[h] = __uint_as_float(w << 16);
            p1[h] = __uint_as_float(w & 0xffff0000u);
        }
        #pragma unroll
        for (int i = 0; i < 12; i++) {
            float s0 = 0.f, s1 = 0.f;
            #pragma unroll
            for (int h = 0; h < 12; h++) {
                float th = th_s[h * 12 + i];
                s0 = fmaf(th, p0[h], s0);
                s1 = fmaf(th, p1[h], s1);
            }
            float a0 = fmaf((s0 - l_mean[i]) * l_rstd[i], lsc.x, lbs.x);
            float a1 = fmaf((s1 - l_mean[i]) * l_rstd[i], lsc.y, lbs.y);
            Pw[i * 512 + jj * 256 + t] = (u32)f2bf(a0) | ((u32)f2bf(a1) << 16);
        }
    }
    __syncthreads();

    // ---- coalesced store back ----
    #pragma unroll
    for (int it = 0; it < 6; it++) {
        int c = t + it * 256;             // 0..1535, 1536 uint4 chunks
        int h = c >> 7, off = (c & 127) * 8;
        *(uint4*)(P + (((size_t)(b * NH + h)) * NSEQ + q) * NSEQ + off) =
            *(uint4*)&Praw[h][off];
    }
}

// ---------------------------------------------------------------------------
// av_mfma: out[b][k][i*64+d] = sum_q A[b][i][q][k] * V[b][i][q][d] via MFMA.
// Both operands staged TRANSPOSED into LDS (contraction q contiguous):
// register 2x2 micro-transpose -> b32 LDS writes; q-stride padded to 66.
// Block: (b, i, 64-k-tile); 4 waves as 2x2 quadrants of 32k x 32d.
// ---------------------------------------------------------------------------
__global__ __launch_bounds__(256) void av_mfma(
    const unsigned short* __restrict__ A, const unsigned short* __restrict__ V,
    float* __restrict__ out)
{
    const int b  = blockIdx.z;
    const int i  = blockIdx.y;
    const int k0 = blockIdx.x * 64;
    const int t  = threadIdx.x;
    const int wave = t >> 6, lane = t & 63;
    const int m = lane & 15, g = lane >> 4;

    __shared__ __align__(16) u32 At[64 * 33];   // [k][q/2], row stride 33 uints
    __shared__ __align__(16) u32 Vt[64 * 33];   // [d][q/2]

    const unsigned short* Ai = A + ((size_t)(b * NH + i)) * NSEQ * NSEQ;
    const unsigned short* Vi = V + ((size_t)(b * NH + i)) * NSEQ * DH;

    const int wk = (wave >> 1) * 32;   // k quadrant within 64
    const int wd = (wave & 1) * 32;    // d quadrant within 64

    floatx4 acc[2][2] = {};

    for (int q0 = 0; q0 < NSEQ; q0 += 64) {
        ushort4 a0[2], a1[2], v0[2], v1[2];
        #pragma unroll
        for (int l = 0; l < 2; l++) {
            int c = t + l * 256;          // 0..511
            int k4 = (c & 15) * 4;        // 64 k
            int qp = c >> 4;              // 0..31 q-pairs
            a0[l] = *(const ushort4*)(Ai + (size_t)(q0 + 2 * qp)     * NSEQ + k0 + k4);
            a1[l] = *(const ushort4*)(Ai + (size_t)(q0 + 2 * qp + 1) * NSEQ + k0 + k4);
            v0[l] = *(const ushort4*)(Vi + (size_t)(q0 + 2 * qp)     * DH + k4);
            v1[l] = *(const ushort4*)(Vi + (size_t)(q0 + 2 * qp + 1) * DH + k4);
        }
        __syncthreads();
        #pragma unroll
        for (int l = 0; l < 2; l++) {
            int c = t + l * 256;
            int k4 = (c & 15) * 4;
            int qp = c >> 4;
            const unsigned short* pa0 = (const unsigned short*)&a0[l];
            const unsigned short* pa1 = (const unsigned short*)&a1[l];
            const unsigned short* pv0 = (const unsigned short*)&v0[l];
            const unsigned short* pv1 = (const unsigned short*)&v1[l];
            #pragma unroll
            for (int j = 0; j < 4; j++) {
                At[(k4 + j) * 33 + qp] = (u32)pa0[j] | ((u32)pa1[j] << 16);
                Vt[(k4 + j) * 33 + qp] = (u32)pv0[j] | ((u32)pv1[j] << 16);
            }
        }
        __syncthreads();

        #pragma unroll
        for (int ks = 0; ks < 2; ks++) {          // two 32-q MFMA K-steps
            const int qo = ks * 16 + g * 4;       // uint offset within row
            bf16x8 af[2], bf[2];
            #pragma unroll
            for (int mt = 0; mt < 2; mt++) {
                const u32* r = &At[(wk + mt * 16 + m) * 33 + qo];
                uint4 w; w.x = r[0]; w.y = r[1]; w.z = r[2]; w.w = r[3];
                af[mt] = *(bf16x8*)&w;
            }
            #pragma unroll
            for (int nt = 0; nt < 2; nt++) {
                const u32* r = &Vt[(wd + nt * 16 + m) * 33 + qo];
                uint4 w; w.x = r[0]; w.y = r[1]; w.z = r[2]; w.w = r[3];
                bf[nt] = *(bf16x8*)&w;
            }
            #pragma unroll
            for (int mt = 0; mt < 2; mt++)
                #pragma unroll
                for (int nt = 0; nt < 2; nt++)
                    acc[mt][nt] = __builtin_amdgcn_mfma_f32_16x16x32_bf16(
                        af[mt], bf[nt], acc[mt][nt], 0, 0, 0);
        }
    }

    #pragma unroll
    for (int mt = 0; mt < 2; mt++) {
        #pragma unroll
        for (int nt = 0; nt < 2; nt++) {
            #pragma unroll
            for (int r = 0; r < 4; r++) {
                int k = k0 + wk + mt * 16 + g * 4 + r;
                int d = wd + nt * 16 + m;
                out[((size_t)(b * NSEQ + k)) * DMODEL + i * DH + d] = acc[mt][nt][r];
            }
        }
    }
}

extern "C" void kernel_launch(void* const* d_in, const int* in_sizes, int n_in,
                              void* d_out, int out_size, void* d_ws, size_t ws_size,
                              hipStream_t stream) {
    const float* x     = (const float*)d_in[0];
    const float* Wq    = (const float*)d_in[1];
    const float* Wk    = (const float*)d_in[2];
    const float* Wv    = (const float*)d_in[3];
    const float* theta = (const float*)d_in[4];
    const float* ln_s  = (const float*)d_in[5];
    const float* ln_b  = (const float*)d_in[6];
    float* out = (float*)d_out;

    char* ws = (char*)d_ws;
    const size_t qsz = (size_t)NB * NSEQ * DMODEL * sizeof(unsigned short); // 6.29 MB
    unsigned short* Q = (unsigned short*)(ws);
    unsigned short* K = (unsigned short*)(ws + qsz);
    unsigned short* V = (unsigned short*)(ws + 2 * qsz);
    unsigned short* P = (unsigned short*)(ws + 3 * qsz);  // 100.7 MB, becomes A in-place
    // xb/Wt live inside the (not yet written) P region: dead before score_gemm
    unsigned short* xb = P;
    unsigned short* Wt = P + (size_t)NB * NSEQ * DMODEL;  // 3 x 768 x 768 bf16

    cast_x<<<dim3(NB * NSEQ * DMODEL / 2048), 256, 0, stream>>>(x, xb);
    tr_w<<<dim3(12, 12, 3), 256, 0, stream>>>(Wq, Wk, Wv, Wt);
    qkv_mfma<<<dim3(NB * NSEQ / 128, DMODEL / 128, 3), 256, 0, stream>>>(
        xb, Wt, Q, K, V);
    score_gemm<<<dim3(NSEQ / 128, NSEQ / 128, NB * NH), 256, 0, stream>>>(Q, K, P);
    mix_ln<<<dim3(NSEQ, NB), 256, 0, stream>>>(P, theta, ln_s, ln_b);
    av_mfma<<<dim3(NSEQ / 64, NH, NB), 256, 0, stream>>>(P, V, out);
}

// Round 5
// 325.417 us; speedup vs baseline: 3.6206x; 1.3929x over previous
//
#include <hip/hip_runtime.h>

#define NB    4
#define NSEQ  1024
#define DMODEL 768
#define NH    12
#define DH    64

typedef __bf16 bf16x8 __attribute__((ext_vector_type(8)));
typedef float  floatx4 __attribute__((ext_vector_type(4)));
typedef unsigned int u32;

static __device__ __forceinline__ float bf2f(unsigned short u) {
    return __uint_as_float(((unsigned)u) << 16);
}
static __device__ __forceinline__ unsigned short f2bf(float f) {
    unsigned u = __float_as_uint(f);
    u += 0x7FFFu + ((u >> 16) & 1u);   // round-to-nearest-even
    return (unsigned short)(u >> 16);
}

// ---------------------------------------------------------------------------
// cast_x: x fp32 [4096*768] -> bf16
// ---------------------------------------------------------------------------
__global__ __launch_bounds__(256) void cast_x(
    const float* __restrict__ x, unsigned short* __restrict__ xb)
{
    const int g = blockIdx.x * 256 + threadIdx.x;
    const size_t base = (size_t)g * 8;
    float4 a = *(const float4*)(x + base);
    float4 b = *(const float4*)(x + base + 4);
    unsigned short o[8];
    o[0] = f2bf(a.x); o[1] = f2bf(a.y); o[2] = f2bf(a.z); o[3] = f2bf(a.w);
    o[4] = f2bf(b.x); o[5] = f2bf(b.y); o[6] = f2bf(b.z); o[7] = f2bf(b.w);
    *(uint4*)(xb + base) = *(uint4*)o;
}

// ---------------------------------------------------------------------------
// tr_w: W fp32 [768 k][768 c] -> Wt bf16 [768 c][768 k]  (z selects Wq/Wk/Wv)
// ---------------------------------------------------------------------------
__global__ __launch_bounds__(256) void tr_w(
    const float* __restrict__ Wq, const float* __restrict__ Wk,
    const float* __restrict__ Wv, unsigned short* __restrict__ Wt)
{
    const int z  = blockIdx.z;
    const float* __restrict__ W = (z == 0) ? Wq : (z == 1) ? Wk : Wv;
    const int c0 = blockIdx.x * 64;
    const int k0 = blockIdx.y * 64;
    const int t  = threadIdx.x;

    __shared__ float ls[64][65];

    const int lr = t >> 2;
    #pragma unroll
    for (int j = 0; j < 4; j++) {
        int col = (t & 3) * 16 + j * 4;
        float4 v = *(const float4*)(W + (size_t)(k0 + lr) * DMODEL + c0 + col);
        ls[lr][col + 0] = v.x; ls[lr][col + 1] = v.y;
        ls[lr][col + 2] = v.z; ls[lr][col + 3] = v.w;
    }
    __syncthreads();
    const int lc = t >> 2;
    #pragma unroll
    for (int j = 0; j < 4; j++) {
        int kb = (t & 3) * 16 + j * 4;
        ushort4 o;
        o.x = f2bf(ls[kb + 0][lc]); o.y = f2bf(ls[kb + 1][lc]);
        o.z = f2bf(ls[kb + 2][lc]); o.w = f2bf(ls[kb + 3][lc]);
        *(ushort4*)(Wt + (size_t)z * DMODEL * DMODEL + (size_t)(c0 + lc) * DMODEL + k0 + kb) = o;
    }
}

// ---------------------------------------------------------------------------
// qkv_mfma: C[4096][768] = xb @ Wt[z]^T via MFMA bf16, 128x128 tile / block.
// ---------------------------------------------------------------------------
__global__ __launch_bounds__(256) void qkv_mfma(
    const unsigned short* __restrict__ xb, const unsigned short* __restrict__ Wt,
    unsigned short* __restrict__ Q, unsigned short* __restrict__ K,
    unsigned short* __restrict__ V)
{
    const int z  = blockIdx.z;
    const int r0 = blockIdx.x * 128;
    const int c0 = blockIdx.y * 128;
    const int t    = threadIdx.x;
    const int wave = t >> 6, lane = t & 63;
    const int m = lane & 15, g = lane >> 4;

    const unsigned short* __restrict__ B = Wt + (size_t)z * DMODEL * DMODEL;

    __shared__ __align__(16) char sm[36864];
    unsigned short (*As)[40] = (unsigned short(*)[40])sm;            // 128x40
    unsigned short (*Bs)[40] = (unsigned short(*)[40])(sm + 10240);  // 128x40
    unsigned short (*Po)[136] = (unsigned short(*)[136])sm;          // epilogue

    const int wq = (wave >> 1) * 64, wc = (wave & 1) * 64;

    floatx4 acc[4][4] = {};

    for (int k0 = 0; k0 < DMODEL; k0 += 32) {
        uint4 av[2], bv[2];
        #pragma unroll
        for (int i = 0; i < 2; i++) {
            int ci = t + i * 256;          // 0..511
            int row = ci >> 2, off = (ci & 3) * 8;
            av[i] = *(const uint4*)(xb + (size_t)(r0 + row) * DMODEL + k0 + off);
            bv[i] = *(const uint4*)(B  + (size_t)(c0 + row) * DMODEL + k0 + off);
        }
        __syncthreads();
        #pragma unroll
        for (int i = 0; i < 2; i++) {
            int ci = t + i * 256;
            int row = ci >> 2, off = (ci & 3) * 8;
            *(uint4*)&As[row][off] = av[i];
            *(uint4*)&Bs[row][off] = bv[i];
        }
        __syncthreads();

        bf16x8 af[4], bf[4];
        #pragma unroll
        for (int mt = 0; mt < 4; mt++)
            af[mt] = *(const bf16x8*)&As[wq + mt * 16 + m][g * 8];
        #pragma unroll
        for (int nt = 0; nt < 4; nt++)
            bf[nt] = *(const bf16x8*)&Bs[wc + nt * 16 + m][g * 8];
        #pragma unroll
        for (int mt = 0; mt < 4; mt++)
            #pragma unroll
            for (int nt = 0; nt < 4; nt++)
                acc[mt][nt] = __builtin_amdgcn_mfma_f32_16x16x32_bf16(
                    af[mt], bf[nt], acc[mt][nt], 0, 0, 0);
    }

    __syncthreads();
    const float scale = (z == 0) ? 0.125f : 1.0f;
    #pragma unroll
    for (int mt = 0; mt < 4; mt++) {
        #pragma unroll
        for (int nt = 0; nt < 4; nt++) {
            int rloc = wq + mt * 16 + g * 4;
            int cloc = wc + nt * 16 + m;
            #pragma unroll
            for (int r = 0; r < 4; r++)
                Po[rloc + r][cloc] = f2bf(acc[mt][nt][r] * scale);
        }
    }
    __syncthreads();

    #pragma unroll
    for (int i = 0; i < 8; i++) {
        int ci = t + i * 256;             // 0..2047
        int row = ci >> 4, off = (ci & 15) * 8;
        uint4 val = *(uint4*)&Po[row][off];
        if (z == 0) {
            *(uint4*)(Q + (size_t)(r0 + row) * DMODEL + c0 + off) = val;
        } else {
            unsigned short* P = (z == 1) ? K : V;
            int rr = r0 + row;
            int b = rr >> 10, n = rr & 1023;
            int cc = c0 + off;
            int h = cc >> 6, d = cc & 63;
            *(uint4*)(P + (((size_t)b * NH + h) * NSEQ + n) * DH + d) = val;
        }
    }
}

// ---------------------------------------------------------------------------
// score_gemm: per (b,h): S = (Q_h/8) . K_h^T via MFMA, 128x128 tile.
// Writes P = exp(S) unnormalized, bf16, P[b][h][q][k].
// ---------------------------------------------------------------------------
__global__ __launch_bounds__(256) void score_gemm(
    const unsigned short* __restrict__ Q, const unsigned short* __restrict__ K,
    unsigned short* __restrict__ P)
{
    const int bh = blockIdx.z;        // b*12+h
    const int b  = bh / NH, h = bh % NH;
    const int q0 = blockIdx.x * 128;
    const int k0 = blockIdx.y * 128;
    const int t    = threadIdx.x;
    const int wave = t >> 6, lane = t & 63;

    __shared__ __align__(16) char sm[36864];
    unsigned short (*Qs)[72] = (unsigned short(*)[72])sm;            // 128 x 72
    unsigned short (*Ks)[72] = (unsigned short(*)[72])(sm + 18432);  // 128 x 72
    unsigned short (*Po)[136] = (unsigned short(*)[136])sm;          // epilogue reuse

    #pragma unroll
    for (int i = 0; i < 4; i++) {
        int c = t + i * 256;              // 0..1023
        int row = c >> 3, off = (c & 7) * 8;
        uint4 qa = *(const uint4*)(Q + ((size_t)(b * NSEQ + q0 + row)) * DMODEL + h * DH + off);
        uint4 ka = *(const uint4*)(K + (((size_t)bh) * NSEQ + (k0 + row)) * DH + off);
        *(uint4*)&Qs[row][off] = qa;
        *(uint4*)&Ks[row][off] = ka;
    }
    __syncthreads();

    const int wq = (wave >> 1) * 64, wk2 = (wave & 1) * 64;
    const int m = lane & 15, g = lane >> 4;

    floatx4 acc[4][4] = {};
    #pragma unroll
    for (int ds = 0; ds < 2; ds++) {
        const int dd = ds * 32 + g * 8;
        bf16x8 af[4], bf[4];
        #pragma unroll
        for (int mt = 0; mt < 4; mt++)
            af[mt] = *(const bf16x8*)&Qs[wq + mt * 16 + m][dd];
        #pragma unroll
        for (int nt = 0; nt < 4; nt++)
            bf[nt] = *(const bf16x8*)&Ks[wk2 + nt * 16 + m][dd];
        #pragma unroll
        for (int mt = 0; mt < 4; mt++)
            #pragma unroll
            for (int nt = 0; nt < 4; nt++)
                acc[mt][nt] = __builtin_amdgcn_mfma_f32_16x16x32_bf16(
                    af[mt], bf[nt], acc[mt][nt], 0, 0, 0);
    }

    __syncthreads();
    #pragma unroll
    for (int mt = 0; mt < 4; mt++) {
        #pragma unroll
        for (int nt = 0; nt < 4; nt++) {
            int qloc = wq + mt * 16 + g * 4;
            int kloc = wk2 + nt * 16 + m;
            #pragma unroll
            for (int r = 0; r < 4; r++)
                Po[qloc + r][kloc] = f2bf(__expf(acc[mt][nt][r]));
        }
    }
    __syncthreads();

    #pragma unroll
    for (int i = 0; i < 8; i++) {
        int c = t + i * 256;              // 0..2047
        int row = c >> 4, off = (c & 15) * 8;
        *(uint4*)(P + (((size_t)bh * NSEQ) + q0 + row) * NSEQ + k0 + off) =
            *(uint4*)&Po[row][off];
    }
}

// ---------------------------------------------------------------------------
// block-wide reduction of 12 per-thread values (sum), result in out12
// ---------------------------------------------------------------------------
static __device__ __forceinline__ void reduce12(
    const float* v, float* out12, float* red, int t)
{
    const int lane = t & 63, w = t >> 6;
    #pragma unroll
    for (int h = 0; h < 12; h++) {
        float x = v[h];
        #pragma unroll
        for (int off = 32; off > 0; off >>= 1)
            x += __shfl_down(x, off, 64);
        if (lane == 0) red[w * 12 + h] = x;
    }
    __syncthreads();
    if (t < 12) {
        float x = red[t];
        #pragma unroll
        for (int w2 = 1; w2 < 4; w2++) x += red[w2 * 12 + t];
        out12[t] = x;
    }
    __syncthreads();
}

// ---------------------------------------------------------------------------
// mix_stats: per (b,q). Two streaming passes over the 12 P-rows.
// Pass 1: row sums -> softmax denominators l. Pass 2: theta mix -> sum(T^2)
// -> rstd.  LN mean is closed-form: mean[i] = sum_h theta[h,i] / 1024
// (softmax rows sum to 1).  Writes l and rstd to scratch (carved from d_out,
// later fully overwritten by av_mfma).  No LDS park, tiny LDS -> occupancy.
// ---------------------------------------------------------------------------
__global__ __launch_bounds__(256) void mix_stats(
    const unsigned short* __restrict__ P, const float* __restrict__ theta,
    float* __restrict__ Lbuf, float* __restrict__ Rbuf)
{
    const int q = blockIdx.x, b = blockIdx.y, t = threadIdx.x;
    __shared__ float th_s[144], red[48], l_l[12], l_s2[12];

    const unsigned short* Pq = P + ((size_t)b * NH * NSEQ + q) * NSEQ;

    // ---- pass 1: row sums ----
    float r12[12];
    #pragma unroll
    for (int h = 0; h < NH; h++) {
        ushort4 u = *(const ushort4*)(Pq + (size_t)h * NSEQ * NSEQ + 4 * t);
        r12[h] = (bf2f(u.x) + bf2f(u.y)) + (bf2f(u.z) + bf2f(u.w));
    }
    reduce12(r12, l_l, red, t);

    if (t < 144) th_s[t] = theta[t] * (1.0f / l_l[t / 12]);
    __syncthreads();

    // ---- pass 2: mix (2 k-columns at a time), accumulate sum(T^2) ----
    float sT2[12] = {};
    #pragma unroll
    for (int jj = 0; jj < 2; jj++) {
        float p0[12], p1[12];
        #pragma unroll
        for (int h = 0; h < NH; h++) {
            u32 w = *(const u32*)(Pq + (size_t)h * NSEQ * NSEQ + jj * 512 + 2 * t);
            p0[h] = __uint_as_float(w << 16);
            p1[h] = __uint_as_float(w & 0xffff0000u);
        }
        #pragma unroll
        for (int i = 0; i < 12; i++) {
            float s0 = 0.f, s1 = 0.f;
            #pragma unroll
            for (int h = 0; h < 12; h++) {
                float th = th_s[h * 12 + i];
                s0 = fmaf(th, p0[h], s0);
                s1 = fmaf(th, p1[h], s1);
            }
            sT2[i] = fmaf(s0, s0, fmaf(s1, s1, sT2[i]));
        }
    }
    reduce12(sT2, l_s2, red, t);

    if (t < 12) {
        float mean = 0.f;
        #pragma unroll
        for (int h = 0; h < 12; h++) mean += theta[h * 12 + t];
        mean *= (1.0f / 1024.0f);
        float var = l_s2[t] * (1.0f / 1024.0f) - mean * mean;
        Lbuf[(b * NH + t) * NSEQ + q] = l_l[t];
        Rbuf[(b * NH + t) * NSEQ + q] = rsqrtf(var + 1e-6f);
    }
}

// ---------------------------------------------------------------------------
// mix_apply: per (b,q). Pure streaming: load 12 heads x 4 k-cols, mix with
// theta/l, LayerNorm with precomputed mean/rstd, write A bf16 in place.
// No reductions, no LDS round-trip; threads own disjoint k-columns.
// ---------------------------------------------------------------------------
__global__ __launch_bounds__(256) void mix_apply(
    unsigned short* __restrict__ P, const float* __restrict__ theta,
    const float* __restrict__ Lbuf, const float* __restrict__ Rbuf,
    const float* __restrict__ ln_scale, const float* __restrict__ ln_bias)
{
    const int q = blockIdx.x, b = blockIdx.y, t = threadIdx.x;
    __shared__ float th_s[144], l_mean[12], l_rstd[12], l_l[12];

    if (t < 12) {
        l_l[t]    = Lbuf[(b * NH + t) * NSEQ + q];
        l_rstd[t] = Rbuf[(b * NH + t) * NSEQ + q];
        float mean = 0.f;
        #pragma unroll
        for (int h = 0; h < 12; h++) mean += theta[h * 12 + t];
        l_mean[t] = mean * (1.0f / 1024.0f);
    }
    __syncthreads();
    if (t < 144) th_s[t] = theta[t] * (1.0f / l_l[t / 12]);
    __syncthreads();

    unsigned short* Pq = P + ((size_t)b * NH * NSEQ + q) * NSEQ;
    const int k0 = 4 * t;
    float4 lsc = *(const float4*)(ln_scale + k0);
    float4 lbs = *(const float4*)(ln_bias + k0);

    float p[12][4];
    #pragma unroll
    for (int h = 0; h < NH; h++) {
        ushort4 u = *(const ushort4*)(Pq + (size_t)h * NSEQ * NSEQ + k0);
        p[h][0] = bf2f(u.x); p[h][1] = bf2f(u.y);
        p[h][2] = bf2f(u.z); p[h][3] = bf2f(u.w);
    }
    #pragma unroll
    for (int i = 0; i < 12; i++) {
        float s0 = 0.f, s1 = 0.f, s2 = 0.f, s3 = 0.f;
        #pragma unroll
        for (int h = 0; h < 12; h++) {
            float th = th_s[h * 12 + i];
            s0 = fmaf(th, p[h][0], s0); s1 = fmaf(th, p[h][1], s1);
            s2 = fmaf(th, p[h][2], s2); s3 = fmaf(th, p[h][3], s3);
        }
        float mm = l_mean[i], rs = l_rstd[i];
        ushort4 o;
        o.x = f2bf(fmaf((s0 - mm) * rs, lsc.x, lbs.x));
        o.y = f2bf(fmaf((s1 - mm) * rs, lsc.y, lbs.y));
        o.z = f2bf(fmaf((s2 - mm) * rs, lsc.z, lbs.z));
        o.w = f2bf(fmaf((s3 - mm) * rs, lsc.w, lbs.w));
        *(ushort4*)(Pq + (size_t)i * NSEQ * NSEQ + k0) = o;
    }
}

// ---------------------------------------------------------------------------
// av_mfma: out[b][k][i*64+d] = sum_q A[b][i][q][k] * V[b][i][q][d] via MFMA.
// Both operands staged TRANSPOSED into LDS (contraction q contiguous).
// ---------------------------------------------------------------------------
__global__ __launch_bounds__(256) void av_mfma(
    const unsigned short* __restrict__ A, const unsigned short* __restrict__ V,
    float* __restrict__ out)
{
    const int b  = blockIdx.z;
    const int i  = blockIdx.y;
    const int k0 = blockIdx.x * 64;
    const int t  = threadIdx.x;
    const int wave = t >> 6, lane = t & 63;
    const int m = lane & 15, g = lane >> 4;

    __shared__ __align__(16) u32 At[64 * 33];   // [k][q/2], row stride 33 uints
    __shared__ __align__(16) u32 Vt[64 * 33];   // [d][q/2]

    const unsigned short* Ai = A + ((size_t)(b * NH + i)) * NSEQ * NSEQ;
    const unsigned short* Vi = V + ((size_t)(b * NH + i)) * NSEQ * DH;

    const int wk = (wave >> 1) * 32;
    const int wd = (wave & 1) * 32;

    floatx4 acc[2][2] = {};

    for (int q0 = 0; q0 < NSEQ; q0 += 64) {
        ushort4 a0[2], a1[2], v0[2], v1[2];
        #pragma unroll
        for (int l = 0; l < 2; l++) {
            int c = t + l * 256;          // 0..511
            int k4 = (c & 15) * 4;
            int qp = c >> 4;
            a0[l] = *(const ushort4*)(Ai + (size_t)(q0 + 2 * qp)     * NSEQ + k0 + k4);
            a1[l] = *(const ushort4*)(Ai + (size_t)(q0 + 2 * qp + 1) * NSEQ + k0 + k4);
            v0[l] = *(const ushort4*)(Vi + (size_t)(q0 + 2 * qp)     * DH + k4);
            v1[l] = *(const ushort4*)(Vi + (size_t)(q0 + 2 * qp + 1) * DH + k4);
        }
        __syncthreads();
        #pragma unroll
        for (int l = 0; l < 2; l++) {
            int c = t + l * 256;
            int k4 = (c & 15) * 4;
            int qp = c >> 4;
            const unsigned short* pa0 = (const unsigned short*)&a0[l];
            const unsigned short* pa1 = (const unsigned short*)&a1[l];
            const unsigned short* pv0 = (const unsigned short*)&v0[l];
            const unsigned short* pv1 = (const unsigned short*)&v1[l];
            #pragma unroll
            for (int j = 0; j < 4; j++) {
                At[(k4 + j) * 33 + qp] = (u32)pa0[j] | ((u32)pa1[j] << 16);
                Vt[(k4 + j) * 33 + qp] = (u32)pv0[j] | ((u32)pv1[j] << 16);
            }
        }
        __syncthreads();

        #pragma unroll
        for (int ks = 0; ks < 2; ks++) {
            const int qo = ks * 16 + g * 4;
            bf16x8 af[2], bf[2];
            #pragma unroll
            for (int mt = 0; mt < 2; mt++) {
                const u32* r = &At[(wk + mt * 16 + m) * 33 + qo];
                uint4 w; w.x = r[0]; w.y = r[1]; w.z = r[2]; w.w = r[3];
                af[mt] = *(bf16x8*)&w;
            }
            #pragma unroll
            for (int nt = 0; nt < 2; nt++) {
                const u32* r = &Vt[(wd + nt * 16 + m) * 33 + qo];
                uint4 w; w.x = r[0]; w.y = r[1]; w.z = r[2]; w.w = r[3];
                bf[nt] = *(bf16x8*)&w;
            }
            #pragma unroll
            for (int mt = 0; mt < 2; mt++)
                #pragma unroll
                for (int nt = 0; nt < 2; nt++)
                    acc[mt][nt] = __builtin_amdgcn_mfma_f32_16x16x32_bf16(
                        af[mt], bf[nt], acc[mt][nt], 0, 0, 0);
        }
    }

    #pragma unroll
    for (int mt = 0; mt < 2; mt++) {
        #pragma unroll
        for (int nt = 0; nt < 2; nt++) {
            #pragma unroll
            for (int r = 0; r < 4; r++) {
                int k = k0 + wk + mt * 16 + g * 4 + r;
                int d = wd + nt * 16 + m;
                out[((size_t)(b * NSEQ + k)) * DMODEL + i * DH + d] = acc[mt][nt][r];
            }
        }
    }
}

extern "C" void kernel_launch(void* const* d_in, const int* in_sizes, int n_in,
                              void* d_out, int out_size, void* d_ws, size_t ws_size,
                              hipStream_t stream) {
    const float* x     = (const float*)d_in[0];
    const float* Wq    = (const float*)d_in[1];
    const float* Wk    = (const float*)d_in[2];
    const float* Wv    = (const float*)d_in[3];
    const float* theta = (const float*)d_in[4];
    const float* ln_s  = (const float*)d_in[5];
    const float* ln_b  = (const float*)d_in[6];
    float* out = (float*)d_out;

    char* ws = (char*)d_ws;
    const size_t qsz = (size_t)NB * NSEQ * DMODEL * sizeof(unsigned short); // 6.29 MB
    unsigned short* Q = (unsigned short*)(ws);
    unsigned short* K = (unsigned short*)(ws + qsz);
    unsigned short* V = (unsigned short*)(ws + 2 * qsz);
    unsigned short* P = (unsigned short*)(ws + 3 * qsz);  // 100.7 MB, becomes A in-place
    // xb/Wt live inside the (not yet written) P region: dead before score_gemm
    unsigned short* xb = P;
    unsigned short* Wt = P + (size_t)NB * NSEQ * DMODEL;  // 3 x 768 x 768 bf16

    // l / rstd scratch carved from d_out (12.6 MB): av_mfma fully overwrites
    // d_out afterwards, and both are dead by then.
    float* Lbuf = out;                       // [NB*NH*NSEQ]
    float* Rbuf = out + NB * NH * NSEQ;      // [NB*NH*NSEQ]

    cast_x<<<dim3(NB * NSEQ * DMODEL / 2048), 256, 0, stream>>>(x, xb);
    tr_w<<<dim3(12, 12, 3), 256, 0, stream>>>(Wq, Wk, Wv, Wt);
    qkv_mfma<<<dim3(NB * NSEQ / 128, DMODEL / 128, 3), 256, 0, stream>>>(
        xb, Wt, Q, K, V);
    score_gemm<<<dim3(NSEQ / 128, NSEQ / 128, NB * NH), 256, 0, stream>>>(Q, K, P);
    mix_stats<<<dim3(NSEQ, NB), 256, 0, stream>>>(P, theta, Lbuf, Rbuf);
    mix_apply<<<dim3(NSEQ, NB), 256, 0, stream>>>(P, theta, Lbuf, Rbuf, ln_s, ln_b);
    av_mfma<<<dim3(NSEQ / 64, NH, NB), 256, 0, stream>>>(P, V, out);
}

// Round 6
// 317.097 us; speedup vs baseline: 3.7156x; 1.0262x over previous
//
#include <hip/hip_runtime.h>

#define NB    4
#define NSEQ  1024
#define DMODEL 768
#define NH    12
#define DH    64

typedef __bf16 bf16x8 __attribute__((ext_vector_type(8)));
typedef float  floatx4 __attribute__((ext_vector_type(4)));
typedef unsigned int u32;

static __device__ __forceinline__ float bf2f(unsigned short u) {
    return __uint_as_float(((unsigned)u) << 16);
}
static __device__ __forceinline__ unsigned short f2bf(float f) {
    unsigned u = __float_as_uint(f);
    u += 0x7FFFu + ((u >> 16) & 1u);   // round-to-nearest-even
    return (unsigned short)(u >> 16);
}

// ---------------------------------------------------------------------------
// cast_x: x fp32 [4096*768] -> bf16
// ---------------------------------------------------------------------------
__global__ __launch_bounds__(256) void cast_x(
    const float* __restrict__ x, unsigned short* __restrict__ xb)
{
    const int g = blockIdx.x * 256 + threadIdx.x;
    const size_t base = (size_t)g * 8;
    float4 a = *(const float4*)(x + base);
    float4 b = *(const float4*)(x + base + 4);
    unsigned short o[8];
    o[0] = f2bf(a.x); o[1] = f2bf(a.y); o[2] = f2bf(a.z); o[3] = f2bf(a.w);
    o[4] = f2bf(b.x); o[5] = f2bf(b.y); o[6] = f2bf(b.z); o[7] = f2bf(b.w);
    *(uint4*)(xb + base) = *(uint4*)o;
}

// ---------------------------------------------------------------------------
// tr_w: W fp32 [768 k][768 c] -> Wt bf16 [768 c][768 k]  (z selects Wq/Wk/Wv)
// ---------------------------------------------------------------------------
__global__ __launch_bounds__(256) void tr_w(
    const float* __restrict__ Wq, const float* __restrict__ Wk,
    const float* __restrict__ Wv, unsigned short* __restrict__ Wt)
{
    const int z  = blockIdx.z;
    const float* __restrict__ W = (z == 0) ? Wq : (z == 1) ? Wk : Wv;
    const int c0 = blockIdx.x * 64;
    const int k0 = blockIdx.y * 64;
    const int t  = threadIdx.x;

    __shared__ float ls[64][65];

    const int lr = t >> 2;
    #pragma unroll
    for (int j = 0; j < 4; j++) {
        int col = (t & 3) * 16 + j * 4;
        float4 v = *(const float4*)(W + (size_t)(k0 + lr) * DMODEL + c0 + col);
        ls[lr][col + 0] = v.x; ls[lr][col + 1] = v.y;
        ls[lr][col + 2] = v.z; ls[lr][col + 3] = v.w;
    }
    __syncthreads();
    const int lc = t >> 2;
    #pragma unroll
    for (int j = 0; j < 4; j++) {
        int kb = (t & 3) * 16 + j * 4;
        ushort4 o;
        o.x = f2bf(ls[kb + 0][lc]); o.y = f2bf(ls[kb + 1][lc]);
        o.z = f2bf(ls[kb + 2][lc]); o.w = f2bf(ls[kb + 3][lc]);
        *(ushort4*)(Wt + (size_t)z * DMODEL * DMODEL + (size_t)(c0 + lc) * DMODEL + k0 + kb) = o;
    }
}

// ---------------------------------------------------------------------------
// qkv_mfma v2: C[4096][768] = xb @ Wt[z]^T via MFMA bf16.
// 64x128 tile / block -> 1152 blocks (4.5/CU). Register-prefetch double
// buffering: next K-step's global loads issue before this step's MFMAs,
// so the vmcnt wait lands one full iteration after issue.
// ---------------------------------------------------------------------------
__global__ __launch_bounds__(256) void qkv_mfma(
    const unsigned short* __restrict__ xb, const unsigned short* __restrict__ Wt,
    unsigned short* __restrict__ Q, unsigned short* __restrict__ K,
    unsigned short* __restrict__ V)
{
    const int z  = blockIdx.z;
    const int r0 = blockIdx.x * 64;
    const int c0 = blockIdx.y * 128;
    const int t    = threadIdx.x;
    const int wave = t >> 6, lane = t & 63;
    const int m = lane & 15, g = lane >> 4;

    const unsigned short* __restrict__ B = Wt + (size_t)z * DMODEL * DMODEL;

    __shared__ __align__(16) char sm[17408];
    unsigned short (*As)[40] = (unsigned short(*)[40])sm;            // 64x40  (5120 B)
    unsigned short (*Bs)[40] = (unsigned short(*)[40])(sm + 5120);   // 128x40 (10240 B)
    unsigned short (*Po)[136] = (unsigned short(*)[136])sm;          // 64x136 epilogue

    const int wm = (wave >> 1) * 32;   // row quadrant (0/32)
    const int wn = (wave & 1) * 64;    // col quadrant (0/64)

    // staging indices
    const int ar = t >> 2, ao = (t & 3) * 8;          // A: 64 rows x 4 chunks
    floatx4 acc[2][4] = {};

    uint4 av, bv[2];
    // prefetch k0 = 0
    av = *(const uint4*)(xb + (size_t)(r0 + ar) * DMODEL + ao);
    #pragma unroll
    for (int l = 0; l < 2; l++) {
        int c = t + l * 256;
        int row = c >> 2, off = (c & 3) * 8;
        bv[l] = *(const uint4*)(B + (size_t)(c0 + row) * DMODEL + off);
    }

    for (int kk = 0; kk < DMODEL / 32; kk++) {
        __syncthreads();                 // previous iteration's frag reads done
        *(uint4*)&As[ar][ao] = av;
        #pragma unroll
        for (int l = 0; l < 2; l++) {
            int c = t + l * 256;
            int row = c >> 2, off = (c & 3) * 8;
            *(uint4*)&Bs[row][off] = bv[l];
        }
        __syncthreads();

        // issue next iteration's loads NOW (consumed after next barrier)
        if (kk + 1 < DMODEL / 32) {
            int k0 = (kk + 1) * 32;
            av = *(const uint4*)(xb + (size_t)(r0 + ar) * DMODEL + k0 + ao);
            #pragma unroll
            for (int l = 0; l < 2; l++) {
                int c = t + l * 256;
                int row = c >> 2, off = (c & 3) * 8;
                bv[l] = *(const uint4*)(B + (size_t)(c0 + row) * DMODEL + k0 + off);
            }
        }

        bf16x8 af[2], bf[4];
        #pragma unroll
        for (int mt = 0; mt < 2; mt++)
            af[mt] = *(const bf16x8*)&As[wm + mt * 16 + m][g * 8];
        #pragma unroll
        for (int nt = 0; nt < 4; nt++)
            bf[nt] = *(const bf16x8*)&Bs[wn + nt * 16 + m][g * 8];
        #pragma unroll
        for (int mt = 0; mt < 2; mt++)
            #pragma unroll
            for (int nt = 0; nt < 4; nt++)
                acc[mt][nt] = __builtin_amdgcn_mfma_f32_16x16x32_bf16(
                    af[mt], bf[nt], acc[mt][nt], 0, 0, 0);
    }

    __syncthreads();
    const float scale = (z == 0) ? 0.125f : 1.0f;
    #pragma unroll
    for (int mt = 0; mt < 2; mt++) {
        #pragma unroll
        for (int nt = 0; nt < 4; nt++) {
            int rloc = wm + mt * 16 + g * 4;
            int cloc = wn + nt * 16 + m;
            #pragma unroll
            for (int r = 0; r < 4; r++)
                Po[rloc + r][cloc] = f2bf(acc[mt][nt][r] * scale);
        }
    }
    __syncthreads();

    #pragma unroll
    for (int i = 0; i < 4; i++) {
        int ci = t + i * 256;             // 0..1023 chunks of 8 ushorts
        int row = ci >> 4, off = (ci & 15) * 8;
        uint4 val = *(uint4*)&Po[row][off];
        if (z == 0) {
            *(uint4*)(Q + (size_t)(r0 + row) * DMODEL + c0 + off) = val;
        } else {
            unsigned short* P = (z == 1) ? K : V;
            int rr = r0 + row;
            int b = rr >> 10, n = rr & 1023;
            int cc = c0 + off;
            int h = cc >> 6, d = cc & 63;
            *(uint4*)(P + (((size_t)b * NH + h) * NSEQ + n) * DH + d) = val;
        }
    }
}

// ---------------------------------------------------------------------------
// score_gemm: per (b,h): S = (Q_h/8) . K_h^T via MFMA, 128x128 tile.
// Writes P = exp(S) unnormalized, bf16, P[b][h][q][k].
// ---------------------------------------------------------------------------
__global__ __launch_bounds__(256) void score_gemm(
    const unsigned short* __restrict__ Q, const unsigned short* __restrict__ K,
    unsigned short* __restrict__ P)
{
    const int bh = blockIdx.z;        // b*12+h
    const int b  = bh / NH, h = bh % NH;
    const int q0 = blockIdx.x * 128;
    const int k0 = blockIdx.y * 128;
    const int t    = threadIdx.x;
    const int wave = t >> 6, lane = t & 63;

    __shared__ __align__(16) char sm[36864];
    unsigned short (*Qs)[72] = (unsigned short(*)[72])sm;            // 128 x 72
    unsigned short (*Ks)[72] = (unsigned short(*)[72])(sm + 18432);  // 128 x 72
    unsigned short (*Po)[136] = (unsigned short(*)[136])sm;          // epilogue reuse

    #pragma unroll
    for (int i = 0; i < 4; i++) {
        int c = t + i * 256;              // 0..1023
        int row = c >> 3, off = (c & 7) * 8;
        uint4 qa = *(const uint4*)(Q + ((size_t)(b * NSEQ + q0 + row)) * DMODEL + h * DH + off);
        uint4 ka = *(const uint4*)(K + (((size_t)bh) * NSEQ + (k0 + row)) * DH + off);
        *(uint4*)&Qs[row][off] = qa;
        *(uint4*)&Ks[row][off] = ka;
    }
    __syncthreads();

    const int wq = (wave >> 1) * 64, wk2 = (wave & 1) * 64;
    const int m = lane & 15, g = lane >> 4;

    floatx4 acc[4][4] = {};
    #pragma unroll
    for (int ds = 0; ds < 2; ds++) {
        const int dd = ds * 32 + g * 8;
        bf16x8 af[4], bf[4];
        #pragma unroll
        for (int mt = 0; mt < 4; mt++)
            af[mt] = *(const bf16x8*)&Qs[wq + mt * 16 + m][dd];
        #pragma unroll
        for (int nt = 0; nt < 4; nt++)
            bf[nt] = *(const bf16x8*)&Ks[wk2 + nt * 16 + m][dd];
        #pragma unroll
        for (int mt = 0; mt < 4; mt++)
            #pragma unroll
            for (int nt = 0; nt < 4; nt++)
                acc[mt][nt] = __builtin_amdgcn_mfma_f32_16x16x32_bf16(
                    af[mt], bf[nt], acc[mt][nt], 0, 0, 0);
    }

    __syncthreads();
    #pragma unroll
    for (int mt = 0; mt < 4; mt++) {
        #pragma unroll
        for (int nt = 0; nt < 4; nt++) {
            int qloc = wq + mt * 16 + g * 4;
            int kloc = wk2 + nt * 16 + m;
            #pragma unroll
            for (int r = 0; r < 4; r++)
                Po[qloc + r][kloc] = f2bf(__expf(acc[mt][nt][r]));
        }
    }
    __syncthreads();

    #pragma unroll
    for (int i = 0; i < 8; i++) {
        int c = t + i * 256;              // 0..2047
        int row = c >> 4, off = (c & 15) * 8;
        *(uint4*)(P + (((size_t)bh * NSEQ) + q0 + row) * NSEQ + k0 + off) =
            *(uint4*)&Po[row][off];
    }
}

// ---------------------------------------------------------------------------
// block-wide reduction of 12 per-thread values (sum), result in out12
// ---------------------------------------------------------------------------
static __device__ __forceinline__ void reduce12(
    const float* v, float* out12, float* red, int t)
{
    const int lane = t & 63, w = t >> 6;
    #pragma unroll
    for (int h = 0; h < 12; h++) {
        float x = v[h];
        #pragma unroll
        for (int off = 32; off > 0; off >>= 1)
            x += __shfl_down(x, off, 64);
        if (lane == 0) red[w * 12 + h] = x;
    }
    __syncthreads();
    if (t < 12) {
        float x = red[t];
        #pragma unroll
        for (int w2 = 1; w2 < 4; w2++) x += red[w2 * 12 + t];
        out12[t] = x;
    }
    __syncthreads();
}

// ---------------------------------------------------------------------------
// mix_stats: per (b,q). Two streaming passes over the 12 P-rows.
// Pass 1: row sums -> softmax denominators l. Pass 2: theta mix -> sum(T^2)
// -> rstd.  LN mean closed-form: mean[i] = sum_h theta[h,i] / 1024.
// ---------------------------------------------------------------------------
__global__ __launch_bounds__(256) void mix_stats(
    const unsigned short* __restrict__ P, const float* __restrict__ theta,
    float* __restrict__ Lbuf, float* __restrict__ Rbuf)
{
    const int q = blockIdx.x, b = blockIdx.y, t = threadIdx.x;
    __shared__ float th_s[144], red[48], l_l[12], l_s2[12];

    const unsigned short* Pq = P + ((size_t)b * NH * NSEQ + q) * NSEQ;

    float r12[12];
    #pragma unroll
    for (int h = 0; h < NH; h++) {
        ushort4 u = *(const ushort4*)(Pq + (size_t)h * NSEQ * NSEQ + 4 * t);
        r12[h] = (bf2f(u.x) + bf2f(u.y)) + (bf2f(u.z) + bf2f(u.w));
    }
    reduce12(r12, l_l, red, t);

    if (t < 144) th_s[t] = theta[t] * (1.0f / l_l[t / 12]);
    __syncthreads();

    float sT2[12] = {};
    #pragma unroll
    for (int jj = 0; jj < 2; jj++) {
        float p0[12], p1[12];
        #pragma unroll
        for (int h = 0; h < NH; h++) {
            u32 w = *(const u32*)(Pq + (size_t)h * NSEQ * NSEQ + jj * 512 + 2 * t);
            p0[h] = __uint_as_float(w << 16);
            p1[h] = __uint_as_float(w & 0xffff0000u);
        }
        #pragma unroll
        for (int i = 0; i < 12; i++) {
            float s0 = 0.f, s1 = 0.f;
            #pragma unroll
            for (int h = 0; h < 12; h++) {
                float th = th_s[h * 12 + i];
                s0 = fmaf(th, p0[h], s0);
                s1 = fmaf(th, p1[h], s1);
            }
            sT2[i] = fmaf(s0, s0, fmaf(s1, s1, sT2[i]));
        }
    }
    reduce12(sT2, l_s2, red, t);

    if (t < 12) {
        float mean = 0.f;
        #pragma unroll
        for (int h = 0; h < 12; h++) mean += theta[h * 12 + t];
        mean *= (1.0f / 1024.0f);
        float var = l_s2[t] * (1.0f / 1024.0f) - mean * mean;
        Lbuf[(b * NH + t) * NSEQ + q] = l_l[t];
        Rbuf[(b * NH + t) * NSEQ + q] = rsqrtf(var + 1e-6f);
    }
}

// ---------------------------------------------------------------------------
// mix_apply: per (b,q). Pure streaming: mix + LayerNorm with precomputed
// stats, write A bf16 in place.
// ---------------------------------------------------------------------------
__global__ __launch_bounds__(256) void mix_apply(
    unsigned short* __restrict__ P, const float* __restrict__ theta,
    const float* __restrict__ Lbuf, const float* __restrict__ Rbuf,
    const float* __restrict__ ln_scale, const float* __restrict__ ln_bias)
{
    const int q = blockIdx.x, b = blockIdx.y, t = threadIdx.x;
    __shared__ float th_s[144], l_mean[12], l_rstd[12], l_l[12];

    if (t < 12) {
        l_l[t]    = Lbuf[(b * NH + t) * NSEQ + q];
        l_rstd[t] = Rbuf[(b * NH + t) * NSEQ + q];
        float mean = 0.f;
        #pragma unroll
        for (int h = 0; h < 12; h++) mean += theta[h * 12 + t];
        l_mean[t] = mean * (1.0f / 1024.0f);
    }
    __syncthreads();
    if (t < 144) th_s[t] = theta[t] * (1.0f / l_l[t / 12]);
    __syncthreads();

    unsigned short* Pq = P + ((size_t)b * NH * NSEQ + q) * NSEQ;
    const int k0 = 4 * t;
    float4 lsc = *(const float4*)(ln_scale + k0);
    float4 lbs = *(const float4*)(ln_bias + k0);

    float p[12][4];
    #pragma unroll
    for (int h = 0; h < NH; h++) {
        ushort4 u = *(const ushort4*)(Pq + (size_t)h * NSEQ * NSEQ + k0);
        p[h][0] = bf2f(u.x); p[h][1] = bf2f(u.y);
        p[h][2] = bf2f(u.z); p[h][3] = bf2f(u.w);
    }
    #pragma unroll
    for (int i = 0; i < 12; i++) {
        float s0 = 0.f, s1 = 0.f, s2 = 0.f, s3 = 0.f;
        #pragma unroll
        for (int h = 0; h < 12; h++) {
            float th = th_s[h * 12 + i];
            s0 = fmaf(th, p[h][0], s0); s1 = fmaf(th, p[h][1], s1);
            s2 = fmaf(th, p[h][2], s2); s3 = fmaf(th, p[h][3], s3);
        }
        float mm = l_mean[i], rs = l_rstd[i];
        ushort4 o;
        o.x = f2bf(fmaf((s0 - mm) * rs, lsc.x, lbs.x));
        o.y = f2bf(fmaf((s1 - mm) * rs, lsc.y, lbs.y));
        o.z = f2bf(fmaf((s2 - mm) * rs, lsc.z, lbs.z));
        o.w = f2bf(fmaf((s3 - mm) * rs, lsc.w, lbs.w));
        *(ushort4*)(Pq + (size_t)i * NSEQ * NSEQ + k0) = o;
    }
}

// ---------------------------------------------------------------------------
// av_mfma: out[b][k][i*64+d] = sum_q A[b][i][q][k] * V[b][i][q][d] via MFMA.
// Both operands staged TRANSPOSED into LDS (contraction q contiguous).
// ---------------------------------------------------------------------------
__global__ __launch_bounds__(256) void av_mfma(
    const unsigned short* __restrict__ A, const unsigned short* __restrict__ V,
    float* __restrict__ out)
{
    const int b  = blockIdx.z;
    const int i  = blockIdx.y;
    const int k0 = blockIdx.x * 64;
    const int t  = threadIdx.x;
    const int wave = t >> 6, lane = t & 63;
    const int m = lane & 15, g = lane >> 4;

    __shared__ __align__(16) u32 At[64 * 33];   // [k][q/2], row stride 33 uints
    __shared__ __align__(16) u32 Vt[64 * 33];   // [d][q/2]

    const unsigned short* Ai = A + ((size_t)(b * NH + i)) * NSEQ * NSEQ;
    const unsigned short* Vi = V + ((size_t)(b * NH + i)) * NSEQ * DH;

    const int wk = (wave >> 1) * 32;
    const int wd = (wave & 1) * 32;

    floatx4 acc[2][2] = {};

    for (int q0 = 0; q0 < NSEQ; q0 += 64) {
        ushort4 a0[2], a1[2], v0[2], v1[2];
        #pragma unroll
        for (int l = 0; l < 2; l++) {
            int c = t + l * 256;          // 0..511
            int k4 = (c & 15) * 4;
            int qp = c >> 4;
            a0[l] = *(const ushort4*)(Ai + (size_t)(q0 + 2 * qp)     * NSEQ + k0 + k4);
            a1[l] = *(const ushort4*)(Ai + (size_t)(q0 + 2 * qp + 1) * NSEQ + k0 + k4);
            v0[l] = *(const ushort4*)(Vi + (size_t)(q0 + 2 * qp)     * DH + k4);
            v1[l] = *(const ushort4*)(Vi + (size_t)(q0 + 2 * qp + 1) * DH + k4);
        }
        __syncthreads();
        #pragma unroll
        for (int l = 0; l < 2; l++) {
            int c = t + l * 256;
            int k4 = (c & 15) * 4;
            int qp = c >> 4;
            const unsigned short* pa0 = (const unsigned short*)&a0[l];
            const unsigned short* pa1 = (const unsigned short*)&a1[l];
            const unsigned short* pv0 = (const unsigned short*)&v0[l];
            const unsigned short* pv1 = (const unsigned short*)&v1[l];
            #pragma unroll
            for (int j = 0; j < 4; j++) {
                At[(k4 + j) * 33 + qp] = (u32)pa0[j] | ((u32)pa1[j] << 16);
                Vt[(k4 + j) * 33 + qp] = (u32)pv0[j] | ((u32)pv1[j] << 16);
            }
        }
        __syncthreads();

        #pragma unroll
        for (int ks = 0; ks < 2; ks++) {
            const int qo = ks * 16 + g * 4;
            bf16x8 af[2], bf[2];
            #pragma unroll
            for (int mt = 0; mt < 2; mt++) {
                const u32* r = &At[(wk + mt * 16 + m) * 33 + qo];
                uint4 w; w.x = r[0]; w.y = r[1]; w.z = r[2]; w.w = r[3];
                af[mt] = *(bf16x8*)&w;
            }
            #pragma unroll
            for (int nt = 0; nt < 2; nt++) {
                const u32* r = &Vt[(wd + nt * 16 + m) * 33 + qo];
                uint4 w; w.x = r[0]; w.y = r[1]; w.z = r[2]; w.w = r[3];
                bf[nt] = *(bf16x8*)&w;
            }
            #pragma unroll
            for (int mt = 0; mt < 2; mt++)
                #pragma unroll
                for (int nt = 0; nt < 2; nt++)
                    acc[mt][nt] = __builtin_amdgcn_mfma_f32_16x16x32_bf16(
                        af[mt], bf[nt], acc[mt][nt], 0, 0, 0);
        }
    }

    #pragma unroll
    for (int mt = 0; mt < 2; mt++) {
        #pragma unroll
        for (int nt = 0; nt < 2; nt++) {
            #pragma unroll
            for (int r = 0; r < 4; r++) {
                int k = k0 + wk + mt * 16 + g * 4 + r;
                int d = wd + nt * 16 + m;
                out[((size_t)(b * NSEQ + k)) * DMODEL + i * DH + d] = acc[mt][nt][r];
            }
        }
    }
}

extern "C" void kernel_launch(void* const* d_in, const int* in_sizes, int n_in,
                              void* d_out, int out_size, void* d_ws, size_t ws_size,
                              hipStream_t stream) {
    const float* x     = (const float*)d_in[0];
    const float* Wq    = (const float*)d_in[1];
    const float* Wk    = (const float*)d_in[2];
    const float* Wv    = (const float*)d_in[3];
    const float* theta = (const float*)d_in[4];
    const float* ln_s  = (const float*)d_in[5];
    const float* ln_b  = (const float*)d_in[6];
    float* out = (float*)d_out;

    char* ws = (char*)d_ws;
    const size_t qsz = (size_t)NB * NSEQ * DMODEL * sizeof(unsigned short); // 6.29 MB
    unsigned short* Q = (unsigned short*)(ws);
    unsigned short* K = (unsigned short*)(ws + qsz);
    unsigned short* V = (unsigned short*)(ws + 2 * qsz);
    unsigned short* P = (unsigned short*)(ws + 3 * qsz);  // 100.7 MB, becomes A in-place
    // xb/Wt live inside the (not yet written) P region: dead before score_gemm
    unsigned short* xb = P;
    unsigned short* Wt = P + (size_t)NB * NSEQ * DMODEL;  // 3 x 768 x 768 bf16

    // l / rstd scratch carved from d_out (12.6 MB): av_mfma fully overwrites
    // d_out afterwards, and both are dead by then.
    float* Lbuf = out;                       // [NB*NH*NSEQ]
    float* Rbuf = out + NB * NH * NSEQ;      // [NB*NH*NSEQ]

    cast_x<<<dim3(NB * NSEQ * DMODEL / 2048), 256, 0, stream>>>(x, xb);
    tr_w<<<dim3(12, 12, 3), 256, 0, stream>>>(Wq, Wk, Wv, Wt);
    qkv_mfma<<<dim3(NB * NSEQ / 64, DMODEL / 128, 3), 256, 0, stream>>>(
        xb, Wt, Q, K, V);
    score_gemm<<<dim3(NSEQ / 128, NSEQ / 128, NB * NH), 256, 0, stream>>>(Q, K, P);
    mix_stats<<<dim3(NSEQ, NB), 256, 0, stream>>>(P, theta, Lbuf, Rbuf);
    mix_apply<<<dim3(NSEQ, NB), 256, 0, stream>>>(P, theta, Lbuf, Rbuf, ln_s, ln_b);
    av_mfma<<<dim3(NSEQ / 64, NH, NB), 256, 0, stream>>>(P, V, out);
}

// Round 7
// 251.026 us; speedup vs baseline: 4.6935x; 1.2632x over previous
//
#include <hip/hip_runtime.h>

#define NB    4
#define NSEQ  1024
#define DMODEL 768
#define NH    12
#define DH    64

typedef __bf16 bf16x8 __attribute__((ext_vector_type(8)));
typedef float  floatx4 __attribute__((ext_vector_type(4)));
typedef unsigned int u32;

static __device__ __forceinline__ float bf2f(unsigned short u) {
    return __uint_as_float(((unsigned)u) << 16);
}
static __device__ __forceinline__ unsigned short f2bf(float f) {
    unsigned u = __float_as_uint(f);
    u += 0x7FFFu + ((u >> 16) & 1u);   // round-to-nearest-even
    return (unsigned short)(u >> 16);
}

// async global->LDS DMA, 16B per lane. LDS side must be (wave-uniform base +
// lane*16) — pass per-thread base + t*16 with contiguous lane order.
static __device__ __forceinline__ void gl_lds16(const void* g, void* l) {
    __builtin_amdgcn_global_load_lds(
        (const __attribute__((address_space(1))) unsigned int*)g,
        (__attribute__((address_space(3))) unsigned int*)l, 16, 0, 0);
}

// ---------------------------------------------------------------------------
// cast_x: x fp32 [4096*768] -> bf16
// ---------------------------------------------------------------------------
__global__ __launch_bounds__(256) void cast_x(
    const float* __restrict__ x, unsigned short* __restrict__ xb)
{
    const int g = blockIdx.x * 256 + threadIdx.x;
    const size_t base = (size_t)g * 8;
    float4 a = *(const float4*)(x + base);
    float4 b = *(const float4*)(x + base + 4);
    unsigned short o[8];
    o[0] = f2bf(a.x); o[1] = f2bf(a.y); o[2] = f2bf(a.z); o[3] = f2bf(a.w);
    o[4] = f2bf(b.x); o[5] = f2bf(b.y); o[6] = f2bf(b.z); o[7] = f2bf(b.w);
    *(uint4*)(xb + base) = *(uint4*)o;
}

// ---------------------------------------------------------------------------
// tr_w: W fp32 [768 k][768 c] -> Wt bf16 [768 c][768 k]  (z selects Wq/Wk/Wv)
// ---------------------------------------------------------------------------
__global__ __launch_bounds__(256) void tr_w(
    const float* __restrict__ Wq, const float* __restrict__ Wk,
    const float* __restrict__ Wv, unsigned short* __restrict__ Wt)
{
    const int z  = blockIdx.z;
    const float* __restrict__ W = (z == 0) ? Wq : (z == 1) ? Wk : Wv;
    const int c0 = blockIdx.x * 64;
    const int k0 = blockIdx.y * 64;
    const int t  = threadIdx.x;

    __shared__ float ls[64][65];

    const int lr = t >> 2;
    #pragma unroll
    for (int j = 0; j < 4; j++) {
        int col = (t & 3) * 16 + j * 4;
        float4 v = *(const float4*)(W + (size_t)(k0 + lr) * DMODEL + c0 + col);
        ls[lr][col + 0] = v.x; ls[lr][col + 1] = v.y;
        ls[lr][col + 2] = v.z; ls[lr][col + 3] = v.w;
    }
    __syncthreads();
    const int lc = t >> 2;
    #pragma unroll
    for (int j = 0; j < 4; j++) {
        int kb = (t & 3) * 16 + j * 4;
        ushort4 o;
        o.x = f2bf(ls[kb + 0][lc]); o.y = f2bf(ls[kb + 1][lc]);
        o.z = f2bf(ls[kb + 2][lc]); o.w = f2bf(ls[kb + 3][lc]);
        *(ushort4*)(Wt + (size_t)z * DMODEL * DMODEL + (size_t)(c0 + lc) * DMODEL + k0 + kb) = o;
    }
}

// ---------------------------------------------------------------------------
// qkv_mfma v3 (m97 pattern): C[4096][768] = xb @ Wt[z]^T via MFMA bf16.
// 64x128 tile / block, BK=32, global_load_lds width-16 staging into
// UNPADDED [row][32] LDS (DMA constraint), 2 barriers / K-iter.
// ---------------------------------------------------------------------------
__global__ __launch_bounds__(256) void qkv_mfma(
    const unsigned short* __restrict__ xb, const unsigned short* __restrict__ Wt,
    unsigned short* __restrict__ Q, unsigned short* __restrict__ K,
    unsigned short* __restrict__ V)
{
    const int z  = blockIdx.z;
    const int r0 = blockIdx.x * 64;
    const int c0 = blockIdx.y * 128;
    const int t    = threadIdx.x;
    const int wave = t >> 6, lane = t & 63;
    const int m = lane & 15, g = lane >> 4;

    const unsigned short* __restrict__ B = Wt + (size_t)z * DMODEL * DMODEL;

    __shared__ __align__(16) char sm[17408];
    unsigned short (*As)[32] = (unsigned short(*)[32])sm;            // 64x32  (4096 B)
    unsigned short (*Bs)[32] = (unsigned short(*)[32])(sm + 4096);   // 128x32 (8192 B)
    unsigned short (*Po)[136] = (unsigned short(*)[136])sm;          // 64x136 epilogue

    const int wm = (wave >> 1) * 32;   // row quadrant (0/32)
    const int wn = (wave & 1) * 64;    // col quadrant (0/64)

    floatx4 acc[2][4] = {};

    // per-thread global sources (k advances by 32/iter); LDS dests fixed.
    const unsigned short* ga  = xb + (size_t)(r0 + (t >> 2)) * DMODEL + (t & 3) * 8;
    const unsigned short* gb0 = B  + (size_t)(c0 + (t >> 2)) * DMODEL + (t & 3) * 8;
    const unsigned short* gb1 = B  + (size_t)(c0 + 64 + (t >> 2)) * DMODEL + (t & 3) * 8;
    unsigned short* la  = (unsigned short*)sm + (size_t)t * 8;
    unsigned short* lb0 = (unsigned short*)(sm + 4096) + (size_t)t * 8;
    unsigned short* lb1 = (unsigned short*)(sm + 4096) + (size_t)(t + 256) * 8;

    for (int kk = 0; kk < DMODEL / 32; kk++) {
        gl_lds16(ga  + kk * 32, la);
        gl_lds16(gb0 + kk * 32, lb0);
        gl_lds16(gb1 + kk * 32, lb1);
        __syncthreads();               // drains DMA (vmcnt) + sync

        bf16x8 af[2], bf[4];
        #pragma unroll
        for (int mt = 0; mt < 2; mt++)
            af[mt] = *(const bf16x8*)&As[wm + mt * 16 + m][g * 8];
        #pragma unroll
        for (int nt = 0; nt < 4; nt++)
            bf[nt] = *(const bf16x8*)&Bs[wn + nt * 16 + m][g * 8];
        #pragma unroll
        for (int mt = 0; mt < 2; mt++)
            #pragma unroll
            for (int nt = 0; nt < 4; nt++)
                acc[mt][nt] = __builtin_amdgcn_mfma_f32_16x16x32_bf16(
                    af[mt], bf[nt], acc[mt][nt], 0, 0, 0);
        __syncthreads();               // frag reads done before next overwrite
    }

    const float scale = (z == 0) ? 0.125f : 1.0f;
    #pragma unroll
    for (int mt = 0; mt < 2; mt++) {
        #pragma unroll
        for (int nt = 0; nt < 4; nt++) {
            int rloc = wm + mt * 16 + g * 4;
            int cloc = wn + nt * 16 + m;
            #pragma unroll
            for (int r = 0; r < 4; r++)
                Po[rloc + r][cloc] = f2bf(acc[mt][nt][r] * scale);
        }
    }
    __syncthreads();

    #pragma unroll
    for (int i = 0; i < 4; i++) {
        int ci = t + i * 256;             // 0..1023 chunks of 8 ushorts
        int row = ci >> 4, off = (ci & 15) * 8;
        uint4 val = *(uint4*)&Po[row][off];
        if (z == 0) {
            *(uint4*)(Q + (size_t)(r0 + row) * DMODEL + c0 + off) = val;
        } else {
            unsigned short* P = (z == 1) ? K : V;
            int rr = r0 + row;
            int b = rr >> 10, n = rr & 1023;
            int cc = c0 + off;
            int h = cc >> 6, d = cc & 63;
            *(uint4*)(P + (((size_t)b * NH + h) * NSEQ + n) * DH + d) = val;
        }
    }
}

// ---------------------------------------------------------------------------
// score_gemm: per (b,h): S = (Q_h/8) . K_h^T via MFMA, 128x128 tile.
// Writes P = exp(S) bf16, plus PARTIAL per-q row sums of the tile to
// Lpart[bh][ktile][q] (deterministic softmax-denominator fusion).
// ---------------------------------------------------------------------------
__global__ __launch_bounds__(256) void score_gemm(
    const unsigned short* __restrict__ Q, const unsigned short* __restrict__ K,
    unsigned short* __restrict__ P, float* __restrict__ Lpart)
{
    const int bh = blockIdx.z;        // b*12+h
    const int b  = bh / NH, h = bh % NH;
    const int q0 = blockIdx.x * 128;
    const int k0 = blockIdx.y * 128;
    const int t    = threadIdx.x;
    const int wave = t >> 6, lane = t & 63;

    __shared__ __align__(16) char sm[36864];
    unsigned short (*Qs)[72] = (unsigned short(*)[72])sm;            // 128 x 72
    unsigned short (*Ks)[72] = (unsigned short(*)[72])(sm + 18432);  // 128 x 72
    unsigned short (*Po)[136] = (unsigned short(*)[136])sm;          // epilogue reuse

    #pragma unroll
    for (int i = 0; i < 4; i++) {
        int c = t + i * 256;              // 0..1023
        int row = c >> 3, off = (c & 7) * 8;
        uint4 qa = *(const uint4*)(Q + ((size_t)(b * NSEQ + q0 + row)) * DMODEL + h * DH + off);
        uint4 ka = *(const uint4*)(K + (((size_t)bh) * NSEQ + (k0 + row)) * DH + off);
        *(uint4*)&Qs[row][off] = qa;
        *(uint4*)&Ks[row][off] = ka;
    }
    __syncthreads();

    const int wq = (wave >> 1) * 64, wk2 = (wave & 1) * 64;
    const int m = lane & 15, g = lane >> 4;

    floatx4 acc[4][4] = {};
    #pragma unroll
    for (int ds = 0; ds < 2; ds++) {
        const int dd = ds * 32 + g * 8;
        bf16x8 af[4], bf[4];
        #pragma unroll
        for (int mt = 0; mt < 4; mt++)
            af[mt] = *(const bf16x8*)&Qs[wq + mt * 16 + m][dd];
        #pragma unroll
        for (int nt = 0; nt < 4; nt++)
            bf[nt] = *(const bf16x8*)&Ks[wk2 + nt * 16 + m][dd];
        #pragma unroll
        for (int mt = 0; mt < 4; mt++)
            #pragma unroll
            for (int nt = 0; nt < 4; nt++)
                acc[mt][nt] = __builtin_amdgcn_mfma_f32_16x16x32_bf16(
                    af[mt], bf[nt], acc[mt][nt], 0, 0, 0);
    }

    __syncthreads();
    #pragma unroll
    for (int mt = 0; mt < 4; mt++) {
        #pragma unroll
        for (int nt = 0; nt < 4; nt++) {
            int qloc = wq + mt * 16 + g * 4;
            int kloc = wk2 + nt * 16 + m;
            #pragma unroll
            for (int r = 0; r < 4; r++)
                Po[qloc + r][kloc] = f2bf(__expf(acc[mt][nt][r]));
        }
    }
    __syncthreads();

    // partial row sums over this k-tile (from the bf16-rounded values, so
    // downstream sum(P)/l == 1 exactly up to fp32 order)
    if (t < 128) {
        float s = 0.f;
        #pragma unroll
        for (int c8 = 0; c8 < 16; c8++) {
            uint4 w = *(uint4*)&Po[t][c8 * 8];
            const unsigned short* pw = (const unsigned short*)&w;
            #pragma unroll
            for (int j = 0; j < 8; j++) s += bf2f(pw[j]);
        }
        Lpart[((size_t)bh * 8 + blockIdx.y) * NSEQ + q0 + t] = s;
    }

    #pragma unroll
    for (int i = 0; i < 8; i++) {
        int c = t + i * 256;              // 0..2047
        int row = c >> 4, off = (c & 15) * 8;
        *(uint4*)(P + (((size_t)bh * NSEQ) + q0 + row) * NSEQ + k0 + off) =
            *(uint4*)&Po[row][off];
    }
}

// ---------------------------------------------------------------------------
// block-wide reduction of 12 per-thread values (sum), result in out12
// ---------------------------------------------------------------------------
static __device__ __forceinline__ void reduce12(
    const float* v, float* out12, float* red, int t)
{
    const int lane = t & 63, w = t >> 6;
    #pragma unroll
    for (int h = 0; h < 12; h++) {
        float x = v[h];
        #pragma unroll
        for (int off = 32; off > 0; off >>= 1)
            x += __shfl_down(x, off, 64);
        if (lane == 0) red[w * 12 + h] = x;
    }
    __syncthreads();
    if (t < 12) {
        float x = red[t];
        #pragma unroll
        for (int w2 = 1; w2 < 4; w2++) x += red[w2 * 12 + t];
        out12[t] = x;
    }
    __syncthreads();
}

// ---------------------------------------------------------------------------
// mix_stats: per (b,q). l from Lpart (8 floats/head); one streaming pass
// over P for sum(T^2) -> rstd. LN mean closed-form: sum_h theta[h,i]/1024.
// ---------------------------------------------------------------------------
__global__ __launch_bounds__(256) void mix_stats(
    const unsigned short* __restrict__ P, const float* __restrict__ theta,
    const float* __restrict__ Lpart, float* __restrict__ Lbuf,
    float* __restrict__ Rbuf)
{
    const int q = blockIdx.x, b = blockIdx.y, t = threadIdx.x;
    __shared__ float th_s[144], red[48], l_l[12], l_s2[12];

    if (t < 12) {
        float s = 0.f;
        #pragma unroll
        for (int kt = 0; kt < 8; kt++)
            s += Lpart[(((size_t)(b * NH + t)) * 8 + kt) * NSEQ + q];
        l_l[t] = s;
    }
    __syncthreads();
    if (t < 144) th_s[t] = theta[t] * (1.0f / l_l[t / 12]);
    __syncthreads();

    const unsigned short* Pq = P + ((size_t)b * NH * NSEQ + q) * NSEQ;

    float sT2[12] = {};
    #pragma unroll
    for (int jj = 0; jj < 2; jj++) {
        float p0[12], p1[12];
        #pragma unroll
        for (int h = 0; h < NH; h++) {
            u32 w = *(const u32*)(Pq + (size_t)h * NSEQ * NSEQ + jj * 512 + 2 * t);
            p0[h] = __uint_as_float(w << 16);
            p1[h] = __uint_as_float(w & 0xffff0000u);
        }
        #pragma unroll
        for (int i = 0; i < 12; i++) {
            float s0 = 0.f, s1 = 0.f;
            #pragma unroll
            for (int h = 0; h < 12; h++) {
                float th = th_s[h * 12 + i];
                s0 = fmaf(th, p0[h], s0);
                s1 = fmaf(th, p1[h], s1);
            }
            sT2[i] = fmaf(s0, s0, fmaf(s1, s1, sT2[i]));
        }
    }
    reduce12(sT2, l_s2, red, t);

    if (t < 12) {
        float mean = 0.f;
        #pragma unroll
        for (int h = 0; h < 12; h++) mean += theta[h * 12 + t];
        mean *= (1.0f / 1024.0f);
        float var = l_s2[t] * (1.0f / 1024.0f) - mean * mean;
        Lbuf[(b * NH + t) * NSEQ + q] = l_l[t];
        Rbuf[(b * NH + t) * NSEQ + q] = rsqrtf(var + 1e-6f);
    }
}

// ---------------------------------------------------------------------------
// mix_apply: per (b,q). Pure streaming: mix + LayerNorm with precomputed
// stats, write A bf16 in place.
// ---------------------------------------------------------------------------
__global__ __launch_bounds__(256) void mix_apply(
    unsigned short* __restrict__ P, const float* __restrict__ theta,
    const float* __restrict__ Lbuf, const float* __restrict__ Rbuf,
    const float* __restrict__ ln_scale, const float* __restrict__ ln_bias)
{
    const int q = blockIdx.x, b = blockIdx.y, t = threadIdx.x;
    __shared__ float th_s[144], l_mean[12], l_rstd[12], l_l[12];

    if (t < 12) {
        l_l[t]    = Lbuf[(b * NH + t) * NSEQ + q];
        l_rstd[t] = Rbuf[(b * NH + t) * NSEQ + q];
        float mean = 0.f;
        #pragma unroll
        for (int h = 0; h < 12; h++) mean += theta[h * 12 + t];
        l_mean[t] = mean * (1.0f / 1024.0f);
    }
    __syncthreads();
    if (t < 144) th_s[t] = theta[t] * (1.0f / l_l[t / 12]);
    __syncthreads();

    unsigned short* Pq = P + ((size_t)b * NH * NSEQ + q) * NSEQ;
    const int k0 = 4 * t;
    float4 lsc = *(const float4*)(ln_scale + k0);
    float4 lbs = *(const float4*)(ln_bias + k0);

    float p[12][4];
    #pragma unroll
    for (int h = 0; h < NH; h++) {
        ushort4 u = *(const ushort4*)(Pq + (size_t)h * NSEQ * NSEQ + k0);
        p[h][0] = bf2f(u.x); p[h][1] = bf2f(u.y);
        p[h][2] = bf2f(u.z); p[h][3] = bf2f(u.w);
    }
    #pragma unroll
    for (int i = 0; i < 12; i++) {
        float s0 = 0.f, s1 = 0.f, s2 = 0.f, s3 = 0.f;
        #pragma unroll
        for (int h = 0; h < 12; h++) {
            float th = th_s[h * 12 + i];
            s0 = fmaf(th, p[h][0], s0); s1 = fmaf(th, p[h][1], s1);
            s2 = fmaf(th, p[h][2], s2); s3 = fmaf(th, p[h][3], s3);
        }
        float mm = l_mean[i], rs = l_rstd[i];
        ushort4 o;
        o.x = f2bf(fmaf((s0 - mm) * rs, lsc.x, lbs.x));
        o.y = f2bf(fmaf((s1 - mm) * rs, lsc.y, lbs.y));
        o.z = f2bf(fmaf((s2 - mm) * rs, lsc.z, lbs.z));
        o.w = f2bf(fmaf((s3 - mm) * rs, lsc.w, lbs.w));
        *(ushort4*)(Pq + (size_t)i * NSEQ * NSEQ + k0) = o;
    }
}

// ---------------------------------------------------------------------------
// av_mfma: out[b][k][i*64+d] = sum_q A[b][i][q][k] * V[b][i][q][d] via MFMA.
// Both operands staged TRANSPOSED into LDS (contraction q contiguous).
// ---------------------------------------------------------------------------
__global__ __launch_bounds__(256) void av_mfma(
    const unsigned short* __restrict__ A, const unsigned short* __restrict__ V,
    float* __restrict__ out)
{
    const int b  = blockIdx.z;
    const int i  = blockIdx.y;
    const int k0 = blockIdx.x * 64;
    const int t  = threadIdx.x;
    const int wave = t >> 6, lane = t & 63;
    const int m = lane & 15, g = lane >> 4;

    __shared__ __align__(16) u32 At[64 * 33];   // [k][q/2], row stride 33 uints
    __shared__ __align__(16) u32 Vt[64 * 33];   // [d][q/2]

    const unsigned short* Ai = A + ((size_t)(b * NH + i)) * NSEQ * NSEQ;
    const unsigned short* Vi = V + ((size_t)(b * NH + i)) * NSEQ * DH;

    const int wk = (wave >> 1) * 32;
    const int wd = (wave & 1) * 32;

    floatx4 acc[2][2] = {};

    for (int q0 = 0; q0 < NSEQ; q0 += 64) {
        ushort4 a0[2], a1[2], v0[2], v1[2];
        #pragma unroll
        for (int l = 0; l < 2; l++) {
            int c = t + l * 256;          // 0..511
            int k4 = (c & 15) * 4;
            int qp = c >> 4;
            a0[l] = *(const ushort4*)(Ai + (size_t)(q0 + 2 * qp)     * NSEQ + k0 + k4);
            a1[l] = *(const ushort4*)(Ai + (size_t)(q0 + 2 * qp + 1) * NSEQ + k0 + k4);
            v0[l] = *(const ushort4*)(Vi + (size_t)(q0 + 2 * qp)     * DH + k4);
            v1[l] = *(const ushort4*)(Vi + (size_t)(q0 + 2 * qp + 1) * DH + k4);
        }
        __syncthreads();
        #pragma unroll
        for (int l = 0; l < 2; l++) {
            int c = t + l * 256;
            int k4 = (c & 15) * 4;
            int qp = c >> 4;
            const unsigned short* pa0 = (const unsigned short*)&a0[l];
            const unsigned short* pa1 = (const unsigned short*)&a1[l];
            const unsigned short* pv0 = (const unsigned short*)&v0[l];
            const unsigned short* pv1 = (const unsigned short*)&v1[l];
            #pragma unroll
            for (int j = 0; j < 4; j++) {
                At[(k4 + j) * 33 + qp] = (u32)pa0[j] | ((u32)pa1[j] << 16);
                Vt[(k4 + j) * 33 + qp] = (u32)pv0[j] | ((u32)pv1[j] << 16);
            }
        }
        __syncthreads();

        #pragma unroll
        for (int ks = 0; ks < 2; ks++) {
            const int qo = ks * 16 + g * 4;
            bf16x8 af[2], bf[2];
            #pragma unroll
            for (int mt = 0; mt < 2; mt++) {
                const u32* r = &At[(wk + mt * 16 + m) * 33 + qo];
                uint4 w; w.x = r[0]; w.y = r[1]; w.z = r[2]; w.w = r[3];
                af[mt] = *(bf16x8*)&w;
            }
            #pragma unroll
            for (int nt = 0; nt < 2; nt++) {
                const u32* r = &Vt[(wd + nt * 16 + m) * 33 + qo];
                uint4 w; w.x = r[0]; w.y = r[1]; w.z = r[2]; w.w = r[3];
                bf[nt] = *(bf16x8*)&w;
            }
            #pragma unroll
            for (int mt = 0; mt < 2; mt++)
                #pragma unroll
                for (int nt = 0; nt < 2; nt++)
                    acc[mt][nt] = __builtin_amdgcn_mfma_f32_16x16x32_bf16(
                        af[mt], bf[nt], acc[mt][nt], 0, 0, 0);
        }
    }

    #pragma unroll
    for (int mt = 0; mt < 2; mt++) {
        #pragma unroll
        for (int nt = 0; nt < 2; nt++) {
            #pragma unroll
            for (int r = 0; r < 4; r++) {
                int k = k0 + wk + mt * 16 + g * 4 + r;
                int d = wd + nt * 16 + m;
                out[((size_t)(b * NSEQ + k)) * DMODEL + i * DH + d] = acc[mt][nt][r];
            }
        }
    }
}

extern "C" void kernel_launch(void* const* d_in, const int* in_sizes, int n_in,
                              void* d_out, int out_size, void* d_ws, size_t ws_size,
                              hipStream_t stream) {
    const float* x     = (const float*)d_in[0];
    const float* Wq    = (const float*)d_in[1];
    const float* Wk    = (const float*)d_in[2];
    const float* Wv    = (const float*)d_in[3];
    const float* theta = (const float*)d_in[4];
    const float* ln_s  = (const float*)d_in[5];
    const float* ln_b  = (const float*)d_in[6];
    float* out = (float*)d_out;

    char* ws = (char*)d_ws;
    const size_t qsz = (size_t)NB * NSEQ * DMODEL * sizeof(unsigned short); // 6.29 MB
    unsigned short* Q = (unsigned short*)(ws);
    unsigned short* K = (unsigned short*)(ws + qsz);
    unsigned short* V = (unsigned short*)(ws + 2 * qsz);
    unsigned short* P = (unsigned short*)(ws + 3 * qsz);  // 100.7 MB, becomes A in-place
    // xb/Wt live inside the (not yet written) P region: dead before score_gemm
    unsigned short* xb = P;
    unsigned short* Wt = P + (size_t)NB * NSEQ * DMODEL;  // 3 x 768 x 768 bf16

    // scratch carved from d_out (12.6 MB; av_mfma fully overwrites it last):
    //   Lbuf [48K floats] + Rbuf [48K] + Lpart [48*8*1024 = 393K floats]
    float* Lbuf  = out;
    float* Rbuf  = out + NB * NH * NSEQ;
    float* Lpart = out + 2 * NB * NH * NSEQ;

    cast_x<<<dim3(NB * NSEQ * DMODEL / 2048), 256, 0, stream>>>(x, xb);
    tr_w<<<dim3(12, 12, 3), 256, 0, stream>>>(Wq, Wk, Wv, Wt);
    qkv_mfma<<<dim3(NB * NSEQ / 64, DMODEL / 128, 3), 256, 0, stream>>>(
        xb, Wt, Q, K, V);
    score_gemm<<<dim3(NSEQ / 128, NSEQ / 128, NB * NH), 256, 0, stream>>>(Q, K, P, Lpart);
    mix_stats<<<dim3(NSEQ, NB), 256, 0, stream>>>(P, theta, Lpart, Lbuf, Rbuf);
    mix_apply<<<dim3(NSEQ, NB), 256, 0, stream>>>(P, theta, Lbuf, Rbuf, ln_s, ln_b);
    av_mfma<<<dim3(NSEQ / 64, NH, NB), 256, 0, stream>>>(P, V, out);
}

// Round 8
// 238.284 us; speedup vs baseline: 4.9445x; 1.0535x over previous
//
#include <hip/hip_runtime.h>

#define NB    4
#define NSEQ  1024
#define DMODEL 768
#define NH    12
#define DH    64

typedef __bf16 bf16x8 __attribute__((ext_vector_type(8)));
typedef float  floatx4 __attribute__((ext_vector_type(4)));
typedef unsigned int u32;

static __device__ __forceinline__ float bf2f(unsigned short u) {
    return __uint_as_float(((unsigned)u) << 16);
}
static __device__ __forceinline__ unsigned short f2bf(float f) {
    unsigned u = __float_as_uint(f);
    u += 0x7FFFu + ((u >> 16) & 1u);   // round-to-nearest-even
    return (unsigned short)(u >> 16);
}

// async global->LDS DMA, 16B per lane. LDS side must be (wave-uniform base +
// lane*16) — pass per-thread base + t*16 with contiguous lane order.
static __device__ __forceinline__ void gl_lds16(const void* g, void* l) {
    __builtin_amdgcn_global_load_lds(
        (const __attribute__((address_space(1))) unsigned int*)g,
        (__attribute__((address_space(3))) unsigned int*)l, 16, 0, 0);
}

// ---------------------------------------------------------------------------
// cast_x: x fp32 [4096*768] -> bf16
// ---------------------------------------------------------------------------
__global__ __launch_bounds__(256) void cast_x(
    const float* __restrict__ x, unsigned short* __restrict__ xb)
{
    const int g = blockIdx.x * 256 + threadIdx.x;
    const size_t base = (size_t)g * 8;
    float4 a = *(const float4*)(x + base);
    float4 b = *(const float4*)(x + base + 4);
    unsigned short o[8];
    o[0] = f2bf(a.x); o[1] = f2bf(a.y); o[2] = f2bf(a.z); o[3] = f2bf(a.w);
    o[4] = f2bf(b.x); o[5] = f2bf(b.y); o[6] = f2bf(b.z); o[7] = f2bf(b.w);
    *(uint4*)(xb + base) = *(uint4*)o;
}

// ---------------------------------------------------------------------------
// tr_w: W fp32 [768 k][768 c] -> Wt bf16 [768 c][768 k]  (z selects Wq/Wk/Wv)
// ---------------------------------------------------------------------------
__global__ __launch_bounds__(256) void tr_w(
    const float* __restrict__ Wq, const float* __restrict__ Wk,
    const float* __restrict__ Wv, unsigned short* __restrict__ Wt)
{
    const int z  = blockIdx.z;
    const float* __restrict__ W = (z == 0) ? Wq : (z == 1) ? Wk : Wv;
    const int c0 = blockIdx.x * 64;
    const int k0 = blockIdx.y * 64;
    const int t  = threadIdx.x;

    __shared__ float ls[64][65];

    const int lr = t >> 2;
    #pragma unroll
    for (int j = 0; j < 4; j++) {
        int col = (t & 3) * 16 + j * 4;
        float4 v = *(const float4*)(W + (size_t)(k0 + lr) * DMODEL + c0 + col);
        ls[lr][col + 0] = v.x; ls[lr][col + 1] = v.y;
        ls[lr][col + 2] = v.z; ls[lr][col + 3] = v.w;
    }
    __syncthreads();
    const int lc = t >> 2;
    #pragma unroll
    for (int j = 0; j < 4; j++) {
        int kb = (t & 3) * 16 + j * 4;
        ushort4 o;
        o.x = f2bf(ls[kb + 0][lc]); o.y = f2bf(ls[kb + 1][lc]);
        o.z = f2bf(ls[kb + 2][lc]); o.w = f2bf(ls[kb + 3][lc]);
        *(ushort4*)(Wt + (size_t)z * DMODEL * DMODEL + (size_t)(c0 + lc) * DMODEL + k0 + kb) = o;
    }
}

// ---------------------------------------------------------------------------
// qkv_mfma v3 (m97 pattern): C[4096][768] = xb @ Wt[z]^T via MFMA bf16.
// 64x128 tile / block, BK=32, global_load_lds width-16 staging into
// UNPADDED [row][32] LDS (DMA constraint), 2 barriers / K-iter.
// ---------------------------------------------------------------------------
__global__ __launch_bounds__(256) void qkv_mfma(
    const unsigned short* __restrict__ xb, const unsigned short* __restrict__ Wt,
    unsigned short* __restrict__ Q, unsigned short* __restrict__ K,
    unsigned short* __restrict__ V)
{
    const int z  = blockIdx.z;
    const int r0 = blockIdx.x * 64;
    const int c0 = blockIdx.y * 128;
    const int t    = threadIdx.x;
    const int wave = t >> 6, lane = t & 63;
    const int m = lane & 15, g = lane >> 4;

    const unsigned short* __restrict__ B = Wt + (size_t)z * DMODEL * DMODEL;

    __shared__ __align__(16) char sm[17408];
    unsigned short (*As)[32] = (unsigned short(*)[32])sm;            // 64x32
    unsigned short (*Bs)[32] = (unsigned short(*)[32])(sm + 4096);   // 128x32
    unsigned short (*Po)[136] = (unsigned short(*)[136])sm;          // epilogue

    const int wm = (wave >> 1) * 32;
    const int wn = (wave & 1) * 64;

    floatx4 acc[2][4] = {};

    const unsigned short* ga  = xb + (size_t)(r0 + (t >> 2)) * DMODEL + (t & 3) * 8;
    const unsigned short* gb0 = B  + (size_t)(c0 + (t >> 2)) * DMODEL + (t & 3) * 8;
    const unsigned short* gb1 = B  + (size_t)(c0 + 64 + (t >> 2)) * DMODEL + (t & 3) * 8;
    unsigned short* la  = (unsigned short*)sm + (size_t)t * 8;
    unsigned short* lb0 = (unsigned short*)(sm + 4096) + (size_t)t * 8;
    unsigned short* lb1 = (unsigned short*)(sm + 4096) + (size_t)(t + 256) * 8;

    for (int kk = 0; kk < DMODEL / 32; kk++) {
        gl_lds16(ga  + kk * 32, la);
        gl_lds16(gb0 + kk * 32, lb0);
        gl_lds16(gb1 + kk * 32, lb1);
        __syncthreads();

        bf16x8 af[2], bf[4];
        #pragma unroll
        for (int mt = 0; mt < 2; mt++)
            af[mt] = *(const bf16x8*)&As[wm + mt * 16 + m][g * 8];
        #pragma unroll
        for (int nt = 0; nt < 4; nt++)
            bf[nt] = *(const bf16x8*)&Bs[wn + nt * 16 + m][g * 8];
        #pragma unroll
        for (int mt = 0; mt < 2; mt++)
            #pragma unroll
            for (int nt = 0; nt < 4; nt++)
                acc[mt][nt] = __builtin_amdgcn_mfma_f32_16x16x32_bf16(
                    af[mt], bf[nt], acc[mt][nt], 0, 0, 0);
        __syncthreads();
    }

    const float scale = (z == 0) ? 0.125f : 1.0f;
    #pragma unroll
    for (int mt = 0; mt < 2; mt++) {
        #pragma unroll
        for (int nt = 0; nt < 4; nt++) {
            int rloc = wm + mt * 16 + g * 4;
            int cloc = wn + nt * 16 + m;
            #pragma unroll
            for (int r = 0; r < 4; r++)
                Po[rloc + r][cloc] = f2bf(acc[mt][nt][r] * scale);
        }
    }
    __syncthreads();

    #pragma unroll
    for (int i = 0; i < 4; i++) {
        int ci = t + i * 256;
        int row = ci >> 4, off = (ci & 15) * 8;
        uint4 val = *(uint4*)&Po[row][off];
        if (z == 0) {
            *(uint4*)(Q + (size_t)(r0 + row) * DMODEL + c0 + off) = val;
        } else {
            unsigned short* P = (z == 1) ? K : V;
            int rr = r0 + row;
            int b = rr >> 10, n = rr & 1023;
            int cc = c0 + off;
            int h = cc >> 6, d = cc & 63;
            *(uint4*)(P + (((size_t)b * NH + h) * NSEQ + n) * DH + d) = val;
        }
    }
}

// ---------------------------------------------------------------------------
// score_gemm: per (b,h): S = (Q_h/8) . K_h^T via MFMA, 128x128 tile.
// Writes P = exp(S) bf16 + partial per-q row sums to Lpart[bh][ktile][q].
// ---------------------------------------------------------------------------
__global__ __launch_bounds__(256) void score_gemm(
    const unsigned short* __restrict__ Q, const unsigned short* __restrict__ K,
    unsigned short* __restrict__ P, float* __restrict__ Lpart)
{
    const int bh = blockIdx.z;        // b*12+h
    const int b  = bh / NH, h = bh % NH;
    const int q0 = blockIdx.x * 128;
    const int k0 = blockIdx.y * 128;
    const int t    = threadIdx.x;
    const int wave = t >> 6, lane = t & 63;

    __shared__ __align__(16) char sm[36864];
    unsigned short (*Qs)[72] = (unsigned short(*)[72])sm;            // 128 x 72
    unsigned short (*Ks)[72] = (unsigned short(*)[72])(sm + 18432);  // 128 x 72
    unsigned short (*Po)[136] = (unsigned short(*)[136])sm;          // epilogue reuse

    #pragma unroll
    for (int i = 0; i < 4; i++) {
        int c = t + i * 256;              // 0..1023
        int row = c >> 3, off = (c & 7) * 8;
        uint4 qa = *(const uint4*)(Q + ((size_t)(b * NSEQ + q0 + row)) * DMODEL + h * DH + off);
        uint4 ka = *(const uint4*)(K + (((size_t)bh) * NSEQ + (k0 + row)) * DH + off);
        *(uint4*)&Qs[row][off] = qa;
        *(uint4*)&Ks[row][off] = ka;
    }
    __syncthreads();

    const int wq = (wave >> 1) * 64, wk2 = (wave & 1) * 64;
    const int m = lane & 15, g = lane >> 4;

    floatx4 acc[4][4] = {};
    #pragma unroll
    for (int ds = 0; ds < 2; ds++) {
        const int dd = ds * 32 + g * 8;
        bf16x8 af[4], bf[4];
        #pragma unroll
        for (int mt = 0; mt < 4; mt++)
            af[mt] = *(const bf16x8*)&Qs[wq + mt * 16 + m][dd];
        #pragma unroll
        for (int nt = 0; nt < 4; nt++)
            bf[nt] = *(const bf16x8*)&Ks[wk2 + nt * 16 + m][dd];
        #pragma unroll
        for (int mt = 0; mt < 4; mt++)
            #pragma unroll
            for (int nt = 0; nt < 4; nt++)
                acc[mt][nt] = __builtin_amdgcn_mfma_f32_16x16x32_bf16(
                    af[mt], bf[nt], acc[mt][nt], 0, 0, 0);
    }

    __syncthreads();
    #pragma unroll
    for (int mt = 0; mt < 4; mt++) {
        #pragma unroll
        for (int nt = 0; nt < 4; nt++) {
            int qloc = wq + mt * 16 + g * 4;
            int kloc = wk2 + nt * 16 + m;
            #pragma unroll
            for (int r = 0; r < 4; r++)
                Po[qloc + r][kloc] = f2bf(__expf(acc[mt][nt][r]));
        }
    }
    __syncthreads();

    if (t < 128) {
        float s = 0.f;
        #pragma unroll
        for (int c8 = 0; c8 < 16; c8++) {
            uint4 w = *(uint4*)&Po[t][c8 * 8];
            const unsigned short* pw = (const unsigned short*)&w;
            #pragma unroll
            for (int j = 0; j < 8; j++) s += bf2f(pw[j]);
        }
        Lpart[((size_t)bh * 8 + blockIdx.y) * NSEQ + q0 + t] = s;
    }

    #pragma unroll
    for (int i = 0; i < 8; i++) {
        int c = t + i * 256;              // 0..2047
        int row = c >> 4, off = (c & 15) * 8;
        *(uint4*)(P + (((size_t)bh * NSEQ) + q0 + row) * NSEQ + k0 + off) =
            *(uint4*)&Po[row][off];
    }
}

// ---------------------------------------------------------------------------
// block-wide reduction of 12 per-thread values (sum), result in out12
// ---------------------------------------------------------------------------
static __device__ __forceinline__ void reduce12(
    const float* v, float* out12, float* red, int t)
{
    const int lane = t & 63, w = t >> 6;
    #pragma unroll
    for (int h = 0; h < 12; h++) {
        float x = v[h];
        #pragma unroll
        for (int off = 32; off > 0; off >>= 1)
            x += __shfl_down(x, off, 64);
        if (lane == 0) red[w * 12 + h] = x;
    }
    __syncthreads();
    if (t < 12) {
        float x = red[t];
        #pragma unroll
        for (int w2 = 1; w2 < 4; w2++) x += red[w2 * 12 + t];
        out12[t] = x;
    }
    __syncthreads();
}

// ---------------------------------------------------------------------------
// mix_fused: per (b,q). Single pass over P: l from Lpart, mean closed-form,
// p[12][4] in registers, theta mix on the fly -> sum(T^2) -> ONE reduce12 ->
// rstd, then recompute the mix and apply LayerNorm, write A bf16 in place.
// Recompute (not cache) of the mix keeps VGPR ~110 for occupancy.
// ---------------------------------------------------------------------------
__global__ __launch_bounds__(256) void mix_fused(
    unsigned short* __restrict__ P, const float* __restrict__ theta,
    const float* __restrict__ Lpart,
    const float* __restrict__ ln_scale, const float* __restrict__ ln_bias)
{
    const int q = blockIdx.x, b = blockIdx.y, t = threadIdx.x;
    __shared__ float th_s[144], red[48], l_l[12], l_s2[12], l_mean[12], l_rstd[12];

    if (t < 12) {
        float s = 0.f;
        #pragma unroll
        for (int kt = 0; kt < 8; kt++)
            s += Lpart[(((size_t)(b * NH + t)) * 8 + kt) * NSEQ + q];
        l_l[t] = s;
        float mean = 0.f;
        #pragma unroll
        for (int h = 0; h < 12; h++) mean += theta[h * 12 + t];
        l_mean[t] = mean * (1.0f / 1024.0f);
    }
    __syncthreads();
    if (t < 144) th_s[t] = theta[t] * (1.0f / l_l[t / 12]);
    __syncthreads();

    unsigned short* Pq = P + ((size_t)b * NH * NSEQ + q) * NSEQ;
    const int k0 = 4 * t;

    float p[12][4];
    #pragma unroll
    for (int h = 0; h < NH; h++) {
        ushort4 u = *(const ushort4*)(Pq + (size_t)h * NSEQ * NSEQ + k0);
        p[h][0] = bf2f(u.x); p[h][1] = bf2f(u.y);
        p[h][2] = bf2f(u.z); p[h][3] = bf2f(u.w);
    }

    // stats: mix on the fly, accumulate sum(T^2)
    float sT2[12];
    #pragma unroll
    for (int i = 0; i < 12; i++) {
        float s0 = 0.f, s1 = 0.f, s2 = 0.f, s3 = 0.f;
        #pragma unroll
        for (int h = 0; h < 12; h++) {
            float th = th_s[h * 12 + i];
            s0 = fmaf(th, p[h][0], s0); s1 = fmaf(th, p[h][1], s1);
            s2 = fmaf(th, p[h][2], s2); s3 = fmaf(th, p[h][3], s3);
        }
        sT2[i] = fmaf(s0, s0, fmaf(s1, s1, fmaf(s2, s2, s3 * s3)));
    }
    reduce12(sT2, l_s2, red, t);
    if (t < 12) {
        float mean = l_mean[t];
        float var  = l_s2[t] * (1.0f / 1024.0f) - mean * mean;
        l_rstd[t] = rsqrtf(var + 1e-6f);
    }
    __syncthreads();

    // apply: recompute mix, LayerNorm, overwrite own columns
    float4 lsc = *(const float4*)(ln_scale + k0);
    float4 lbs = *(const float4*)(ln_bias + k0);
    #pragma unroll
    for (int i = 0; i < 12; i++) {
        float s0 = 0.f, s1 = 0.f, s2 = 0.f, s3 = 0.f;
        #pragma unroll
        for (int h = 0; h < 12; h++) {
            float th = th_s[h * 12 + i];
            s0 = fmaf(th, p[h][0], s0); s1 = fmaf(th, p[h][1], s1);
            s2 = fmaf(th, p[h][2], s2); s3 = fmaf(th, p[h][3], s3);
        }
        float mm = l_mean[i], rs = l_rstd[i];
        ushort4 o;
        o.x = f2bf(fmaf((s0 - mm) * rs, lsc.x, lbs.x));
        o.y = f2bf(fmaf((s1 - mm) * rs, lsc.y, lbs.y));
        o.z = f2bf(fmaf((s2 - mm) * rs, lsc.z, lbs.z));
        o.w = f2bf(fmaf((s3 - mm) * rs, lsc.w, lbs.w));
        *(ushort4*)(Pq + (size_t)i * NSEQ * NSEQ + k0) = o;
    }
}

// ---------------------------------------------------------------------------
// av_mfma: out[b][k][i*64+d] = sum_q A[b][i][q][k] * V[b][i][q][d] via MFMA.
// Both operands staged TRANSPOSED into LDS (contraction q contiguous).
// ---------------------------------------------------------------------------
__global__ __launch_bounds__(256) void av_mfma(
    const unsigned short* __restrict__ A, const unsigned short* __restrict__ V,
    float* __restrict__ out)
{
    const int b  = blockIdx.z;
    const int i  = blockIdx.y;
    const int k0 = blockIdx.x * 64;
    const int t  = threadIdx.x;
    const int wave = t >> 6, lane = t & 63;
    const int m = lane & 15, g = lane >> 4;

    __shared__ __align__(16) u32 At[64 * 33];   // [k][q/2], row stride 33 uints
    __shared__ __align__(16) u32 Vt[64 * 33];   // [d][q/2]

    const unsigned short* Ai = A + ((size_t)(b * NH + i)) * NSEQ * NSEQ;
    const unsigned short* Vi = V + ((size_t)(b * NH + i)) * NSEQ * DH;

    const int wk = (wave >> 1) * 32;
    const int wd = (wave & 1) * 32;

    floatx4 acc[2][2] = {};

    for (int q0 = 0; q0 < NSEQ; q0 += 64) {
        ushort4 a0[2], a1[2], v0[2], v1[2];
        #pragma unroll
        for (int l = 0; l < 2; l++) {
            int c = t + l * 256;          // 0..511
            int k4 = (c & 15) * 4;
            int qp = c >> 4;
            a0[l] = *(const ushort4*)(Ai + (size_t)(q0 + 2 * qp)     * NSEQ + k0 + k4);
            a1[l] = *(const ushort4*)(Ai + (size_t)(q0 + 2 * qp + 1) * NSEQ + k0 + k4);
            v0[l] = *(const ushort4*)(Vi + (size_t)(q0 + 2 * qp)     * DH + k4);
            v1[l] = *(const ushort4*)(Vi + (size_t)(q0 + 2 * qp + 1) * DH + k4);
        }
        __syncthreads();
        #pragma unroll
        for (int l = 0; l < 2; l++) {
            int c = t + l * 256;
            int k4 = (c & 15) * 4;
            int qp = c >> 4;
            const unsigned short* pa0 = (const unsigned short*)&a0[l];
            const unsigned short* pa1 = (const unsigned short*)&a1[l];
            const unsigned short* pv0 = (const unsigned short*)&v0[l];
            const unsigned short* pv1 = (const unsigned short*)&v1[l];
            #pragma unroll
            for (int j = 0; j < 4; j++) {
                At[(k4 + j) * 33 + qp] = (u32)pa0[j] | ((u32)pa1[j] << 16);
                Vt[(k4 + j) * 33 + qp] = (u32)pv0[j] | ((u32)pv1[j] << 16);
            }
        }
        __syncthreads();

        #pragma unroll
        for (int ks = 0; ks < 2; ks++) {
            const int qo = ks * 16 + g * 4;
            bf16x8 af[2], bf[2];
            #pragma unroll
            for (int mt = 0; mt < 2; mt++) {
                const u32* r = &At[(wk + mt * 16 + m) * 33 + qo];
                uint4 w; w.x = r[0]; w.y = r[1]; w.z = r[2]; w.w = r[3];
                af[mt] = *(bf16x8*)&w;
            }
            #pragma unroll
            for (int nt = 0; nt < 2; nt++) {
                const u32* r = &Vt[(wd + nt * 16 + m) * 33 + qo];
                uint4 w; w.x = r[0]; w.y = r[1]; w.z = r[2]; w.w = r[3];
                bf[nt] = *(bf16x8*)&w;
            }
            #pragma unroll
            for (int mt = 0; mt < 2; mt++)
                #pragma unroll
                for (int nt = 0; nt < 2; nt++)
                    acc[mt][nt] = __builtin_amdgcn_mfma_f32_16x16x32_bf16(
                        af[mt], bf[nt], acc[mt][nt], 0, 0, 0);
        }
    }

    #pragma unroll
    for (int mt = 0; mt < 2; mt++) {
        #pragma unroll
        for (int nt = 0; nt < 2; nt++) {
            #pragma unroll
            for (int r = 0; r < 4; r++) {
                int k = k0 + wk + mt * 16 + g * 4 + r;
                int d = wd + nt * 16 + m;
                out[((size_t)(b * NSEQ + k)) * DMODEL + i * DH + d] = acc[mt][nt][r];
            }
        }
    }
}

extern "C" void kernel_launch(void* const* d_in, const int* in_sizes, int n_in,
                              void* d_out, int out_size, void* d_ws, size_t ws_size,
                              hipStream_t stream) {
    const float* x     = (const float*)d_in[0];
    const float* Wq    = (const float*)d_in[1];
    const float* Wk    = (const float*)d_in[2];
    const float* Wv    = (const float*)d_in[3];
    const float* theta = (const float*)d_in[4];
    const float* ln_s  = (const float*)d_in[5];
    const float* ln_b  = (const float*)d_in[6];
    float* out = (float*)d_out;

    char* ws = (char*)d_ws;
    const size_t qsz = (size_t)NB * NSEQ * DMODEL * sizeof(unsigned short); // 6.29 MB
    unsigned short* Q = (unsigned short*)(ws);
    unsigned short* K = (unsigned short*)(ws + qsz);
    unsigned short* V = (unsigned short*)(ws + 2 * qsz);
    unsigned short* P = (unsigned short*)(ws + 3 * qsz);  // 100.7 MB, becomes A in-place
    // xb/Wt live inside the (not yet written) P region: dead before score_gemm
    unsigned short* xb = P;
    unsigned short* Wt = P + (size_t)NB * NSEQ * DMODEL;  // 3 x 768 x 768 bf16

    // Lpart scratch carved from d_out (av_mfma fully overwrites d_out last)
    float* Lpart = out;                      // [48 * 8 * 1024 floats]

    cast_x<<<dim3(NB * NSEQ * DMODEL / 2048), 256, 0, stream>>>(x, xb);
    tr_w<<<dim3(12, 12, 3), 256, 0, stream>>>(Wq, Wk, Wv, Wt);
    qkv_mfma<<<dim3(NB * NSEQ / 64, DMODEL / 128, 3), 256, 0, stream>>>(
        xb, Wt, Q, K, V);
    score_gemm<<<dim3(NSEQ / 128, NSEQ / 128, NB * NH), 256, 0, stream>>>(Q, K, P, Lpart);
    mix_fused<<<dim3(NSEQ, NB), 256, 0, stream>>>(P, theta, Lpart, ln_s, ln_b);
    av_mfma<<<dim3(NSEQ / 64, NH, NB), 256, 0, stream>>>(P, V, out);
}